// Round 10
// baseline (722.937 us; speedup 1.0000x reference)
//
#include <hip/hip_runtime.h>
#include <hip/hip_bf16.h>
#include <cstdint>
#include <cstddef>

// LinearCrypto MI355X round 10: barrier-free register GEMM core (A and B
// fragments loaded directly from L2-resident panels; LDS only for epilogue).
// B=64, F=512, L=512, P=96, H=8, hd=64, M=B*512=32768

#define EPS_ATTN 1e-6f
#define EPS_LN   1e-5f
#define EPS_REVIN 1e-5f

typedef __attribute__((ext_vector_type(8))) short bf16x8;
typedef __attribute__((ext_vector_type(4))) float f32x4;
typedef __attribute__((ext_vector_type(8))) unsigned short u16x8;

__device__ __forceinline__ float bf2f(unsigned short u) {
  unsigned int x = ((unsigned int)u) << 16;
  return __builtin_bit_cast(float, x);
}
__device__ __forceinline__ unsigned short f2bf(float f) {
  __hip_bfloat16 h = __float2bfloat16(f);
  return __builtin_bit_cast(unsigned short, h);
}
__device__ __forceinline__ void gload16(const void* g, void* l) {
  __builtin_amdgcn_global_load_lds(
      (const __attribute__((address_space(1))) void*)g,
      (__attribute__((address_space(3))) void*)l, 16, 0, 0);
}

// ---------- RevIN stats + normalized bf16 copy xn (B,F,L) ----------
__global__ __launch_bounds__(256) void revin_xn_k(const float* __restrict__ x,
                                                  const float* __restrict__ rg,
                                                  const float* __restrict__ rb,
                                                  float* __restrict__ meanb,
                                                  float* __restrict__ stdb,
                                                  unsigned short* __restrict__ xn) {
  int wid = threadIdx.x >> 6, lane = threadIdx.x & 63;
  int row = blockIdx.x * 4 + wid;               // b*512 + f
  const float* xr = x + (size_t)row * 512 + lane * 8;
  float4 a = *(const float4*)xr;
  float4 c = *(const float4*)(xr + 4);
  float s1 = a.x + a.y + a.z + a.w + c.x + c.y + c.z + c.w;
  float s2 = a.x * a.x + a.y * a.y + a.z * a.z + a.w * a.w +
             c.x * c.x + c.y * c.y + c.z * c.z + c.w * c.w;
#pragma unroll
  for (int off = 1; off < 64; off <<= 1) { s1 += __shfl_xor(s1, off); s2 += __shfl_xor(s2, off); }
  float m = s1 * (1.f / 512.f);
  float var = fmaxf((s2 - 512.f * m * m) * (1.f / 511.f), 0.f);
  float sd = sqrtf(var) + EPS_REVIN;
  int f = row & 511;
  float sc = rg[f] / sd;
  float of = rb[f] - m * sc;
  u16x8 o;
  o[0] = f2bf(a.x * sc + of); o[1] = f2bf(a.y * sc + of);
  o[2] = f2bf(a.z * sc + of); o[3] = f2bf(a.w * sc + of);
  o[4] = f2bf(c.x * sc + of); o[5] = f2bf(c.y * sc + of);
  o[6] = f2bf(c.z * sc + of); o[7] = f2bf(c.w * sc + of);
  *(u16x8*)(xn + (size_t)row * 512 + lane * 8) = o;
  if (lane == 0) { meanb[row] = m; stdb[row] = sd; }
}

// ---------- fused transpose + LayerNorm: xn (B,F,L) -> abf (B,L,F) LN'd ----------
__global__ __launch_bounds__(256) void tln_k(const unsigned short* __restrict__ xn,
                                             const float* __restrict__ g,
                                             const float* __restrict__ bq,
                                             unsigned short* __restrict__ o16) {
  __shared__ unsigned short Ts[32][528] __attribute__((aligned(16)));
  const int b = blockIdx.y, l0 = blockIdx.x * 32;
  const int tid = threadIdx.x;
#pragma unroll
  for (int it = 0; it < 8; ++it) {
    int idx = it * 256 + tid;
    int f = idx >> 2, lc = (idx & 3) * 8;
    u16x8 v = *(const u16x8*)(xn + ((size_t)b * 512 + f) * 512 + l0 + lc);
#pragma unroll
    for (int j = 0; j < 8; ++j) Ts[lc + j][f] = v[j];
  }
  __syncthreads();
  const int l = tid >> 3, q = tid & 7;
  float s1 = 0.f, s2 = 0.f;
#pragma unroll
  for (int i = 0; i < 8; ++i) {
    int c = (i + q) & 7;
    bf16x8 t = *(const bf16x8*)&Ts[l][q * 64 + c * 8];
#pragma unroll
    for (int j = 0; j < 8; ++j) {
      float x = bf2f((unsigned short)t[j]);
      s1 += x; s2 += x * x;
    }
  }
#pragma unroll
  for (int off = 1; off < 8; off <<= 1) { s1 += __shfl_xor(s1, off); s2 += __shfl_xor(s2, off); }
  float m = s1 * (1.f / 512.f);
  float var = fmaxf(s2 * (1.f / 512.f) - m * m, 0.f);
  float iv = 1.f / sqrtf(var + EPS_LN);
#pragma unroll
  for (int i = 0; i < 8; ++i) {
    int c = (i + q) & 7;
    int f8 = q * 64 + c * 8;
    bf16x8 t = *(const bf16x8*)&Ts[l][f8];
    float4 g0 = *(const float4*)(g + f8);
    float4 g1 = *(const float4*)(g + f8 + 4);
    float4 b0 = *(const float4*)(bq + f8);
    float4 b1 = *(const float4*)(bq + f8 + 4);
    u16x8 o;
    o[0] = f2bf((bf2f((unsigned short)t[0]) - m) * iv * g0.x + b0.x);
    o[1] = f2bf((bf2f((unsigned short)t[1]) - m) * iv * g0.y + b0.y);
    o[2] = f2bf((bf2f((unsigned short)t[2]) - m) * iv * g0.z + b0.z);
    o[3] = f2bf((bf2f((unsigned short)t[3]) - m) * iv * g0.w + b0.w);
    o[4] = f2bf((bf2f((unsigned short)t[4]) - m) * iv * g1.x + b1.x);
    o[5] = f2bf((bf2f((unsigned short)t[5]) - m) * iv * g1.y + b1.y);
    o[6] = f2bf((bf2f((unsigned short)t[6]) - m) * iv * g1.z + b1.z);
    o[7] = f2bf((bf2f((unsigned short)t[7]) - m) * iv * g1.w + b1.w);
    *(u16x8*)&Ts[l][f8] = o;
  }
  __syncthreads();
#pragma unroll
  for (int it = 0; it < 8; ++it) {
    int idx = it * 256 + tid;
    int ll = idx >> 6, f8 = (idx & 63) * 8;
    u16x8 v = *(const u16x8*)&Ts[ll][f8];
    *(u16x8*)(o16 + ((size_t)b * 512 + l0 + ll) * 512 + f8) = v;
  }
}

// ---------- fused LayerNorm bf16 -> bf16 ----------
__global__ __launch_bounds__(256) void ln_k(const unsigned short* __restrict__ in,
                                            const float* __restrict__ g,
                                            const float* __restrict__ bq,
                                            unsigned short* __restrict__ o16) {
  int row = blockIdx.x * 4 + (threadIdx.x >> 6);
  int lane = threadIdx.x & 63;
  u16x8 u = *(const u16x8*)(in + (size_t)row * 512 + lane * 8);
  float v[8];
#pragma unroll
  for (int j = 0; j < 8; ++j) v[j] = bf2f(u[j]);
  float s1 = 0.f, s2 = 0.f;
#pragma unroll
  for (int j = 0; j < 8; ++j) { s1 += v[j]; s2 += v[j] * v[j]; }
#pragma unroll
  for (int off = 1; off < 64; off <<= 1) { s1 += __shfl_xor(s1, off); s2 += __shfl_xor(s2, off); }
  float m = s1 * (1.f / 512.f);
  float var = fmaxf(s2 * (1.f / 512.f) - m * m, 0.f);
  float iv = 1.f / sqrtf(var + EPS_LN);
  float4 g0 = *(const float4*)(g + lane * 8);
  float4 g1 = *(const float4*)(g + lane * 8 + 4);
  float4 b0 = *(const float4*)(bq + lane * 8);
  float4 b1 = *(const float4*)(bq + lane * 8 + 4);
  u16x8 o;
  o[0] = f2bf((v[0] - m) * iv * g0.x + b0.x);
  o[1] = f2bf((v[1] - m) * iv * g0.y + b0.y);
  o[2] = f2bf((v[2] - m) * iv * g0.z + b0.z);
  o[3] = f2bf((v[3] - m) * iv * g0.w + b0.w);
  o[4] = f2bf((v[4] - m) * iv * g1.x + b1.x);
  o[5] = f2bf((v[5] - m) * iv * g1.y + b1.y);
  o[6] = f2bf((v[6] - m) * iv * g1.z + b1.z);
  o[7] = f2bf((v[7] - m) * iv * g1.w + b1.w);
  *(u16x8*)(o16 + (size_t)row * 512 + lane * 8) = o;
}

// ---------- convert 8 (512x512) fp32 weights -> bf16 packed ----------
__global__ __launch_bounds__(256) void wconv_k(const float* w0, const float* w1,
                                               const float* w2, const float* w3,
                                               const float* w4, const float* w5,
                                               const float* w6, const float* w7,
                                               unsigned short* __restrict__ out) {
  const float* srcs[8] = {w0, w1, w2, w3, w4, w5, w6, w7};
  const float* s = srcs[blockIdx.y];
  size_t idx = (size_t)blockIdx.x * 2048 + threadIdx.x * 8;
  float4 v0 = *(const float4*)(s + idx);
  float4 v1 = *(const float4*)(s + idx + 4);
  u16x8 o;
  o[0] = f2bf(v0.x); o[1] = f2bf(v0.y); o[2] = f2bf(v0.z); o[3] = f2bf(v0.w);
  o[4] = f2bf(v1.x); o[5] = f2bf(v1.y); o[6] = f2bf(v1.z); o[7] = f2bf(v1.w);
  *(u16x8*)(out + (size_t)blockIdx.y * 262144 + idx) = o;
}

// ---------- register GEMM core: no LDS, no barriers; frags direct from L2 ----------
// Per load instruction: 16 rows x 64B contiguous (perfect sectors).
__device__ __forceinline__ void gemm_core_reg(const unsigned short* __restrict__ A,
                                              const unsigned short* __restrict__ W,
                                              f32x4 (&acc)[4][4],
                                              int m0, int wrow, int tid) {
  const int w = tid >> 6, lane = tid & 63;
  const int wr = w >> 1, wc = w & 1;
  const int r16 = lane & 15, ks = lane >> 4;
  const unsigned short* Ab = A + (size_t)(m0 + wr * 64 + r16) * 512 + ks * 8;
  const unsigned short* Wb = W + (size_t)(wrow + wc * 64 + r16) * 512 + ks * 8;
#pragma unroll 4
  for (int kc = 0; kc < 16; ++kc) {
    bf16x8 fa[4], fb[4];
#pragma unroll
    for (int i = 0; i < 4; ++i)
      fa[i] = *(const bf16x8*)(Ab + (size_t)i * 16 * 512 + kc * 32);
#pragma unroll
    for (int j = 0; j < 4; ++j)
      fb[j] = *(const bf16x8*)(Wb + (size_t)j * 16 * 512 + kc * 32);
#pragma unroll
    for (int i = 0; i < 4; ++i)
#pragma unroll
      for (int j = 0; j < 4; ++j)
        acc[i][j] = __builtin_amdgcn_mfma_f32_16x16x32_bf16(fa[i], fb[j], acc[i][j], 0, 0, 0);
  }
}

// ---------- templated epilogue (Wo GEMMs): bias -> bf16 LDS tile -> streamed
//            u16x8 writes (+bf16 residual add) ----------
template <int TRANS, int ACT, int RES>
__device__ __forceinline__ void gemm_epilogue(f32x4 (&acc)[4][4],
                                              unsigned short* Cs,   // [128][136]
                                              const float* __restrict__ bias,
                                              const unsigned short* __restrict__ resid,
                                              unsigned short* __restrict__ out,
                                              int m0, int n0, int tid) {
  const int w = tid >> 6, lane = tid & 63;
  const int wr = w >> 1, wc = w & 1;
  const int ro = (lane >> 4) * 4, c16 = lane & 15;
#pragma unroll
  for (int j = 0; j < 4; ++j) {
    int nl = wc * 64 + j * 16 + c16;
    float bi = bias[n0 + nl];
#pragma unroll
    for (int i = 0; i < 4; ++i) {
      int ml = wr * 64 + i * 16 + ro;
#pragma unroll
      for (int r = 0; r < 4; ++r) {
        float v = acc[i][j][r] + bi;
        if constexpr (ACT) v = (v > 0.f) ? v + 1.f : __expf(v);
        if constexpr (TRANS) Cs[nl * 136 + ml + r] = f2bf(v);
        else                 Cs[(ml + r) * 136 + nl] = f2bf(v);
      }
    }
  }
  __syncthreads();
  size_t rowbase; int colbase;
  if constexpr (TRANS) { rowbase = (size_t)((m0 >> 9) * 512 + n0); colbase = m0 & 511; }
  else                 { rowbase = (size_t)m0; colbase = n0; }
#pragma unroll
  for (int c = 0; c < 8; ++c) {
    int idx = c * 256 + tid;
    int rr = idx >> 4, c8 = (idx & 15) * 8;
    u16x8 v = *(const u16x8*)&Cs[rr * 136 + c8];
    size_t gaddr = (rowbase + rr) * 512 + colbase + c8;
    if constexpr (RES) {
      u16x8 rv = *(const u16x8*)(resid + gaddr);
#pragma unroll
      for (int q = 0; q < 8; ++q) v[q] = f2bf(bf2f(v[q]) + bf2f(rv[q]));
    }
    *(u16x8*)(out + gaddr) = v;
  }
}

// ---------- standard GEMM dispatch (Wo): 1D grid 1024, XCD-chunked, n-inner ----------
template <int TRANS, int ACT, int RES>
__global__ __launch_bounds__(256) void gemm_std_k(const unsigned short* __restrict__ A,
                                                  const unsigned short* __restrict__ W,
                                                  const float* __restrict__ bias,
                                                  const unsigned short* __restrict__ resid,
                                                  unsigned short* __restrict__ out) {
  __shared__ unsigned short smem[17408] __attribute__((aligned(16)));  // Cs only
  const int tid = threadIdx.x;
  const int bid = blockIdx.x;
  const int nb = (bid & 7) * 128 + (bid >> 3);   // bijective, 1024 % 8 == 0
  const int m0 = (nb >> 2) * 128;
  const int n0 = (nb & 3) * 128;
  f32x4 acc[4][4] = {};
  gemm_core_reg(A, W, acc, m0, n0, tid);
  gemm_epilogue<TRANS, ACT, RES>(acc, smem, bias, resid, out, m0, n0, tid);
}

// ---------- fused QKV GEMM: grid 3072, 12 n-tiles per A-panel adjacent ----------
__global__ __launch_bounds__(256) void gemm_qkv3_k(const unsigned short* __restrict__ A,
                                                   const unsigned short* __restrict__ Wqkv,
                                                   const float* __restrict__ bq,
                                                   const float* __restrict__ bk,
                                                   const float* __restrict__ bv,
                                                   unsigned short* __restrict__ Q,
                                                   unsigned short* __restrict__ K,
                                                   unsigned short* __restrict__ V) {
  __shared__ unsigned short smem[17408] __attribute__((aligned(16)));  // Cs only
  const int tid = threadIdx.x;
  const unsigned int bid = blockIdx.x;
  const unsigned int nb = (bid & 7) * 384 + (bid >> 3);  // bijective, 3072 % 8 == 0
  const int mi = nb / 12, ni = nb % 12;                  // 12 consecutive share A-panel
  const int m0 = mi * 128;
  const int mat = ni >> 2;                               // 0=Q, 1=K, 2=V
  const int n0 = (ni & 3) * 128;
  f32x4 acc[4][4] = {};
  gemm_core_reg(A, Wqkv, acc, m0, mat * 512 + n0, tid);

  const float* bias = (mat == 0) ? bq : (mat == 1) ? bk : bv;
  unsigned short* out = (mat == 0) ? Q : (mat == 1) ? K : V;
  const bool trans = (mat > 0);
  const bool act = (mat < 2);

  const int w = tid >> 6, lane = tid & 63;
  const int wr = w >> 1, wc = w & 1;
  const int ro = (lane >> 4) * 4, c16 = lane & 15;
  unsigned short* Cs = smem;
#pragma unroll
  for (int j = 0; j < 4; ++j) {
    int nl = wc * 64 + j * 16 + c16;
    float bi = bias[n0 + nl];
#pragma unroll
    for (int i = 0; i < 4; ++i) {
      int ml = wr * 64 + i * 16 + ro;
#pragma unroll
      for (int r = 0; r < 4; ++r) {
        float v = acc[i][j][r] + bi;
        if (act) v = (v > 0.f) ? v + 1.f : __expf(v);
        int row = trans ? nl : (ml + r);
        int col = trans ? (ml + r) : nl;
        Cs[row * 136 + col] = f2bf(v);
      }
    }
  }
  __syncthreads();
  size_t rowbase = trans ? (size_t)((m0 >> 9) * 512 + n0) : (size_t)m0;
  int colbase = trans ? (m0 & 511) : n0;
#pragma unroll
  for (int c = 0; c < 8; ++c) {
    int idx = c * 256 + tid;
    int rr = idx >> 4, c8 = (idx & 15) * 8;
    u16x8 v = *(const u16x8*)&Cs[rr * 136 + c8];
    *(u16x8*)(out + (rowbase + rr) * 512 + colbase + c8) = v;
  }
}

// ---------- KVT[e][d] = sum_n VT[e][n]*KT[d][n]; Z via MFMA-with-ones ----------
__global__ __launch_bounds__(256) void kv_mfma_k(const unsigned short* __restrict__ KT,
                                                 const unsigned short* __restrict__ VT,
                                                 unsigned short* __restrict__ KVTo,
                                                 float* __restrict__ Zo) {
  int bh = blockIdx.x;
  int tid = threadIdx.x, w = tid >> 6, lane = tid & 63;
  int r16 = lane & 15, g = lane >> 4;
  const unsigned short* vb = VT + ((size_t)bh * 64 + w * 16 + r16) * 512 + g * 8;
  const unsigned short* kb = KT + ((size_t)bh * 64 + r16) * 512 + g * 8;
  const short ob = (short)0x3F80;                 // bf16 1.0
  const bf16x8 onesf = {ob, ob, ob, ob, ob, ob, ob, ob};
  f32x4 acc[4] = {};
  f32x4 zacc[4] = {};
  for (int n0 = 0; n0 < 512; n0 += 32) {
    bf16x8 vf = *(const bf16x8*)(vb + n0);
#pragma unroll
    for (int j = 0; j < 4; ++j) {
      bf16x8 kf = *(const bf16x8*)(kb + (size_t)j * 16 * 512 + n0);
      acc[j] = __builtin_amdgcn_mfma_f32_16x16x32_bf16(vf, kf, acc[j], 0, 0, 0);
      zacc[j] = __builtin_amdgcn_mfma_f32_16x16x32_bf16(onesf, kf, zacc[j], 0, 0, 0);
    }
  }
  int e = w * 16 + g * 4;
  unsigned short* kvo = KVTo + (size_t)bh * 4096;
#pragma unroll
  for (int j = 0; j < 4; ++j)
#pragma unroll
    for (int r = 0; r < 4; ++r)
      kvo[(size_t)(e + r) * 64 + j * 16 + r16] = f2bf(acc[j][r]);
  if (w == 0 && g == 0) {
#pragma unroll
    for (int j = 0; j < 4; ++j) Zo[(size_t)bh * 64 + j * 16 + r16] = zacc[j][0];
  }
}

// ---------- O = (Q @ KVT^T)/(Q·Z+eps), in-place over Q ----------
__global__ __launch_bounds__(512) void attn_mfma_k(unsigned short* __restrict__ Q16,
                                                   const unsigned short* __restrict__ KVT,
                                                   const float* __restrict__ Z) {
  __shared__ unsigned short kvs[32768] __attribute__((aligned(16)));
  __shared__ float Zs[512];
  int tid = threadIdx.x;
  int b = blockIdx.x >> 2;
  int m0 = blockIdx.x * 128;
  const unsigned short* kg = KVT + (size_t)b * 32768;
#pragma unroll
  for (int t = 0; t < 8; ++t) {
    int c = tid + t * 512;
    int e = (c >> 3) & 63;
    u16x8 v = *(const u16x8*)(kg + (size_t)c * 8);
    *(u16x8*)((char*)kvs + ((c * 16) ^ ((e & 7) << 4))) = v;
  }
  Zs[tid] = Z[(size_t)b * 512 + tid];
  __syncthreads();

  int w = tid >> 6, lane = tid & 63;
  int r16 = lane & 15, g = lane >> 4;
  unsigned short* qrow = Q16 + (size_t)(m0 + w * 16 + r16) * 512;
  int orow0 = m0 + w * 16 + g * 4;

  for (int h = 0; h < 8; ++h) {
    bf16x8 q0 = *(const bf16x8*)(qrow + h * 64 + g * 8);
    bf16x8 q1 = *(const bf16x8*)(qrow + h * 64 + 32 + g * 8);
    const float* zh = Zs + h * 64;
    float np = 0.f;
#pragma unroll
    for (int q = 0; q < 8; ++q) np = fmaf(bf2f((unsigned short)q0[q]), zh[g * 8 + q], np);
#pragma unroll
    for (int q = 0; q < 8; ++q) np = fmaf(bf2f((unsigned short)q1[q]), zh[32 + g * 8 + q], np);

    f32x4 acc[4] = {};
#pragma unroll
    for (int j = 0; j < 4; ++j) {
      int e = j * 16 + r16;
      int byte0 = h * 8192 + e * 128;
      int sw = (e & 7) << 4;
      bf16x8 k0 = *(const bf16x8*)((char*)kvs + ((byte0 + g * 16) ^ sw));
      bf16x8 k1 = *(const bf16x8*)((char*)kvs + ((byte0 + 64 + g * 16) ^ sw));
      acc[j] = __builtin_amdgcn_mfma_f32_16x16x32_bf16(q0, k0, acc[j], 0, 0, 0);
      acc[j] = __builtin_amdgcn_mfma_f32_16x16x32_bf16(q1, k1, acc[j], 0, 0, 0);
    }
    np += __shfl_xor(np, 16);
    np += __shfl_xor(np, 32);
    float inv = 1.f / (np + EPS_ATTN);
    float inv4[4];
#pragma unroll
    for (int r = 0; r < 4; ++r) inv4[r] = __shfl(inv, g * 4 + r);
#pragma unroll
    for (int j = 0; j < 4; ++j)
#pragma unroll
      for (int r = 0; r < 4; ++r)
        Q16[(size_t)(orow0 + r) * 512 + h * 64 + j * 16 + r16] = f2bf(acc[j][r] * inv4[r]);
  }
}

// ---------- feat_linear via MFMA: per f, Y[b,p] = sum_l h3[b,f,l]*Wlin[f,p,l] ----------
__global__ __launch_bounds__(256) void feat_linear_k(const unsigned short* __restrict__ h3,
                                                     const float* __restrict__ Wlin,
                                                     const float* __restrict__ blin,
                                                     float* __restrict__ Y) {
  __shared__ unsigned short As[64 * 64] __attribute__((aligned(16)));   // 8 KB
  __shared__ unsigned short Bs[96 * 64] __attribute__((aligned(16)));   // 12 KB
  const int f = blockIdx.x;
  const int tid = threadIdx.x;
  const int w = tid >> 6, lane = tid & 63;
  const int r16 = lane & 15, g = lane >> 4;
  const int r8 = lane >> 3, s8 = lane & 7, gs = s8 ^ r8;

  f32x4 acc[6] = {};
  for (int k0 = 0; k0 < 512; k0 += 64) {
#pragma unroll
    for (int c = 0; c < 2; ++c) {
      int row = w * 16 + c * 8 + r8;
      gload16(h3 + ((size_t)row * 512 + f) * 512 + k0 + gs * 8,
              As + (w * 16 + c * 8) * 64);
    }
#pragma unroll
    for (int it = 0; it < 3; ++it) {
      int idx = it * 256 + tid;
      int pp = idx >> 3, sl = idx & 7;
      const float* src = Wlin + ((size_t)f * 96 + pp) * 512 + k0 + sl * 8;
      float4 v0 = *(const float4*)src;
      float4 v1 = *(const float4*)(src + 4);
      u16x8 o;
      o[0] = f2bf(v0.x); o[1] = f2bf(v0.y); o[2] = f2bf(v0.z); o[3] = f2bf(v0.w);
      o[4] = f2bf(v1.x); o[5] = f2bf(v1.y); o[6] = f2bf(v1.z); o[7] = f2bf(v1.w);
      *(u16x8*)&Bs[pp * 64 + (sl ^ (pp & 7)) * 8] = o;
    }
    __syncthreads();
#pragma unroll
    for (int s = 0; s < 2; ++s) {
      int arow = w * 16 + r16;
      bf16x8 fa = *(const bf16x8*)&As[arow * 64 + (((s * 4 + g) ^ (arow & 7)) * 8)];
#pragma unroll
      for (int n = 0; n < 6; ++n) {
        int brow = n * 16 + r16;
        bf16x8 fb = *(const bf16x8*)&Bs[brow * 64 + (((s * 4 + g) ^ (brow & 7)) * 8)];
        acc[n] = __builtin_amdgcn_mfma_f32_16x16x32_bf16(fa, fb, acc[n], 0, 0, 0);
      }
    }
    __syncthreads();
  }
  const int b0 = w * 16 + g * 4;
#pragma unroll
  for (int n = 0; n < 6; ++n) {
    float bi = blin[f * 96 + n * 16 + r16];
#pragma unroll
    for (int r = 0; r < 4; ++r)
      Y[((size_t)(b0 + r) * 512 + f) * 96 + n * 16 + r16] = acc[n][r] + bi;
  }
}

// ---------- final: denorm + projector ----------
__global__ __launch_bounds__(256) void final_out_k(const float* __restrict__ Y,
                                                   const float* __restrict__ meanb,
                                                   const float* __restrict__ stdb,
                                                   const float* __restrict__ rg,
                                                   const float* __restrict__ rb,
                                                   const float* __restrict__ Wproj,
                                                   const float* __restrict__ bproj,
                                                   float* __restrict__ out) {
  int b = blockIdx.x;
  __shared__ float cs[512];
  __shared__ float kred[4];
  int t = threadIdx.x;
  float kpart = 0.f;
  for (int f = t; f < 512; f += 256) {
    float sd = stdb[b * 512 + f], mn = meanb[b * 512 + f];
    float g = rg[f], rbv = rb[f], wp = Wproj[f];
    float c = wp * sd / g;
    cs[f] = c;
    kpart += wp * mn - c * rbv;
  }
#pragma unroll
  for (int off = 32; off; off >>= 1) kpart += __shfl_down(kpart, off);
  int wid = t >> 6, lane = t & 63;
  if (lane == 0) kred[wid] = kpart;
  __syncthreads();
  float K = kred[0] + kred[1] + kred[2] + kred[3] + bproj[0];
  if (t < 96) {
    float acc = 0.f;
    for (int f = 0; f < 512; ++f) acc = fmaf(cs[f], Y[((size_t)b * 512 + f) * 96 + t], acc);
    out[b * 96 + t] = acc + K;
  }
}

extern "C" void kernel_launch(void* const* d_in, const int* in_sizes, int n_in,
                              void* d_out, int out_size, void* d_ws, size_t ws_size,
                              hipStream_t stream) {
  const float* x    = (const float*)d_in[0];
  const float* rg   = (const float*)d_in[1];
  const float* rb   = (const float*)d_in[2];
  const float* n1g  = (const float*)d_in[3];
  const float* n1b  = (const float*)d_in[4];
  const float* n2g  = (const float*)d_in[5];
  const float* n2b  = (const float*)d_in[6];
  const float* tWq  = (const float*)d_in[7];
  const float* tbq  = (const float*)d_in[8];
  const float* tWk  = (const float*)d_in[9];
  const float* tbk  = (const float*)d_in[10];
  const float* tWv  = (const float*)d_in[11];
  const float* tbv  = (const float*)d_in[12];
  const float* tWo  = (const float*)d_in[13];
  const float* tbo  = (const float*)d_in[14];
  const float* fWq  = (const float*)d_in[15];
  const float* fbq  = (const float*)d_in[16];
  const float* fWk  = (const float*)d_in[17];
  const float* fbk  = (const float*)d_in[18];
  const float* fWv  = (const float*)d_in[19];
  const float* fbv  = (const float*)d_in[20];
  const float* fWo  = (const float*)d_in[21];
  const float* fbo  = (const float*)d_in[22];
  const float* Wlin = (const float*)d_in[23];
  const float* blin = (const float*)d_in[24];
  const float* Wprj = (const float*)d_in[25];
  const float* bprj = (const float*)d_in[26];
  float* out = (float*)d_out;

  const size_t SZ = (size_t)64 * 512 * 512;
  char* p = (char*)d_ws;
  unsigned short* xn  = (unsigned short*)p; p += SZ * 2;   // RevIN'd x, (B,F,L)
  unsigned short* h2  = (unsigned short*)p; p += SZ * 2;   // (B,F,L)
  unsigned short* h3  = (unsigned short*)p; p += SZ * 2;   // (B,F,L)
  unsigned short* abf = (unsigned short*)p; p += SZ * 2;   // LN out / ybuf alias
  unsigned short* q16 = (unsigned short*)p; p += SZ * 2;
  unsigned short* k16 = (unsigned short*)p; p += SZ * 2;
  unsigned short* v16 = (unsigned short*)p; p += SZ * 2;
  unsigned short* wbf = (unsigned short*)p; p += (size_t)8 * 262144 * 2;
  unsigned short* kvt = (unsigned short*)p; p += (size_t)512 * 4096 * 2;
  float* z     = (float*)p;         p += (size_t)512 * 64 * 4;
  float* meanb = (float*)p;         p += 32768 * 4;
  float* stdb  = (float*)p;         p += 32768 * 4;
  float* ybuf  = (float*)abf;       // abf dead before feat_linear

  wconv_k<<<dim3(128, 8), 256, 0, stream>>>(tWq, tWk, tWv, tWo, fWq, fWk, fWv, fWo, wbf);
  revin_xn_k<<<8192, 256, 0, stream>>>(x, rg, rb, meanb, stdb, xn);

  // --- temporal attention block (tokens = l, dim = F) ---
  tln_k<<<dim3(16, 64), 256, 0, stream>>>(xn, n1g, n1b, abf);
  gemm_qkv3_k<<<3072, 256, 0, stream>>>(abf, wbf, tbq, tbk, tbv, q16, k16, v16);
  kv_mfma_k<<<512, 256, 0, stream>>>(k16, v16, kvt, z);
  attn_mfma_k<<<256, 512, 0, stream>>>(q16, kvt, z);
  gemm_std_k<1, 0, 1><<<1024, 256, 0, stream>>>(q16, wbf + 3 * 262144, tbo, xn, h2);

  // --- feature attention block (tokens = f, dim = L) ---
  ln_k<<<8192, 256, 0, stream>>>(h2, n2g, n2b, abf);
  gemm_qkv3_k<<<3072, 256, 0, stream>>>(abf, wbf + 4 * 262144, fbq, fbk, fbv, q16, k16, v16);
  kv_mfma_k<<<512, 256, 0, stream>>>(k16, v16, kvt, z);
  attn_mfma_k<<<256, 512, 0, stream>>>(q16, kvt, z);
  gemm_std_k<0, 0, 1><<<1024, 256, 0, stream>>>(q16, wbf + 7 * 262144, fbo, h2, h3);

  // tail
  feat_linear_k<<<512, 256, 0, stream>>>(h3, Wlin, blin, ybuf);
  final_out_k<<<64, 256, 0, stream>>>(ybuf, meanb, stdb, rg, rb, Wprj, bprj, out);
}

// Round 11
// 430.775 us; speedup vs baseline: 1.6782x; 1.6782x over previous
//
#include <hip/hip_runtime.h>
#include <hip/hip_bf16.h>
#include <cstdint>
#include <cstddef>

// LinearCrypto MI355X round 11: wave-private double-buffered GEMM staging,
// counted per-wave vmcnt(8), ZERO barriers in K-loop (guide: "true async
// prefetch with no __syncthreads dependency"). Rest = round 9.
// B=64, F=512, L=512, P=96, H=8, hd=64, M=B*512=32768

#define EPS_ATTN 1e-6f
#define EPS_LN   1e-5f
#define EPS_REVIN 1e-5f

typedef __attribute__((ext_vector_type(8))) short bf16x8;
typedef __attribute__((ext_vector_type(4))) float f32x4;
typedef __attribute__((ext_vector_type(8))) unsigned short u16x8;

__device__ __forceinline__ float bf2f(unsigned short u) {
  unsigned int x = ((unsigned int)u) << 16;
  return __builtin_bit_cast(float, x);
}
__device__ __forceinline__ unsigned short f2bf(float f) {
  __hip_bfloat16 h = __float2bfloat16(f);
  return __builtin_bit_cast(unsigned short, h);
}
__device__ __forceinline__ void gload16(const void* g, void* l) {
  __builtin_amdgcn_global_load_lds(
      (const __attribute__((address_space(1))) void*)g,
      (__attribute__((address_space(3))) void*)l, 16, 0, 0);
}

// ---------- RevIN stats + normalized bf16 copy xn (B,F,L) ----------
__global__ __launch_bounds__(256) void revin_xn_k(const float* __restrict__ x,
                                                  const float* __restrict__ rg,
                                                  const float* __restrict__ rb,
                                                  float* __restrict__ meanb,
                                                  float* __restrict__ stdb,
                                                  unsigned short* __restrict__ xn) {
  int wid = threadIdx.x >> 6, lane = threadIdx.x & 63;
  int row = blockIdx.x * 4 + wid;               // b*512 + f
  const float* xr = x + (size_t)row * 512 + lane * 8;
  float4 a = *(const float4*)xr;
  float4 c = *(const float4*)(xr + 4);
  float s1 = a.x + a.y + a.z + a.w + c.x + c.y + c.z + c.w;
  float s2 = a.x * a.x + a.y * a.y + a.z * a.z + a.w * a.w +
             c.x * c.x + c.y * c.y + c.z * c.z + c.w * c.w;
#pragma unroll
  for (int off = 1; off < 64; off <<= 1) { s1 += __shfl_xor(s1, off); s2 += __shfl_xor(s2, off); }
  float m = s1 * (1.f / 512.f);
  float var = fmaxf((s2 - 512.f * m * m) * (1.f / 511.f), 0.f);
  float sd = sqrtf(var) + EPS_REVIN;
  int f = row & 511;
  float sc = rg[f] / sd;
  float of = rb[f] - m * sc;
  u16x8 o;
  o[0] = f2bf(a.x * sc + of); o[1] = f2bf(a.y * sc + of);
  o[2] = f2bf(a.z * sc + of); o[3] = f2bf(a.w * sc + of);
  o[4] = f2bf(c.x * sc + of); o[5] = f2bf(c.y * sc + of);
  o[6] = f2bf(c.z * sc + of); o[7] = f2bf(c.w * sc + of);
  *(u16x8*)(xn + (size_t)row * 512 + lane * 8) = o;
  if (lane == 0) { meanb[row] = m; stdb[row] = sd; }
}

// ---------- fused transpose + LayerNorm: xn (B,F,L) -> abf (B,L,F) LN'd ----------
__global__ __launch_bounds__(256) void tln_k(const unsigned short* __restrict__ xn,
                                             const float* __restrict__ g,
                                             const float* __restrict__ bq,
                                             unsigned short* __restrict__ o16) {
  __shared__ unsigned short Ts[32][528] __attribute__((aligned(16)));
  const int b = blockIdx.y, l0 = blockIdx.x * 32;
  const int tid = threadIdx.x;
#pragma unroll
  for (int it = 0; it < 8; ++it) {
    int idx = it * 256 + tid;
    int f = idx >> 2, lc = (idx & 3) * 8;
    u16x8 v = *(const u16x8*)(xn + ((size_t)b * 512 + f) * 512 + l0 + lc);
#pragma unroll
    for (int j = 0; j < 8; ++j) Ts[lc + j][f] = v[j];
  }
  __syncthreads();
  const int l = tid >> 3, q = tid & 7;
  float s1 = 0.f, s2 = 0.f;
#pragma unroll
  for (int i = 0; i < 8; ++i) {
    int c = (i + q) & 7;
    bf16x8 t = *(const bf16x8*)&Ts[l][q * 64 + c * 8];
#pragma unroll
    for (int j = 0; j < 8; ++j) {
      float x = bf2f((unsigned short)t[j]);
      s1 += x; s2 += x * x;
    }
  }
#pragma unroll
  for (int off = 1; off < 8; off <<= 1) { s1 += __shfl_xor(s1, off); s2 += __shfl_xor(s2, off); }
  float m = s1 * (1.f / 512.f);
  float var = fmaxf(s2 * (1.f / 512.f) - m * m, 0.f);
  float iv = 1.f / sqrtf(var + EPS_LN);
#pragma unroll
  for (int i = 0; i < 8; ++i) {
    int c = (i + q) & 7;
    int f8 = q * 64 + c * 8;
    bf16x8 t = *(const bf16x8*)&Ts[l][f8];
    float4 g0 = *(const float4*)(g + f8);
    float4 g1 = *(const float4*)(g + f8 + 4);
    float4 b0 = *(const float4*)(bq + f8);
    float4 b1 = *(const float4*)(bq + f8 + 4);
    u16x8 o;
    o[0] = f2bf((bf2f((unsigned short)t[0]) - m) * iv * g0.x + b0.x);
    o[1] = f2bf((bf2f((unsigned short)t[1]) - m) * iv * g0.y + b0.y);
    o[2] = f2bf((bf2f((unsigned short)t[2]) - m) * iv * g0.z + b0.z);
    o[3] = f2bf((bf2f((unsigned short)t[3]) - m) * iv * g0.w + b0.w);
    o[4] = f2bf((bf2f((unsigned short)t[4]) - m) * iv * g1.x + b1.x);
    o[5] = f2bf((bf2f((unsigned short)t[5]) - m) * iv * g1.y + b1.y);
    o[6] = f2bf((bf2f((unsigned short)t[6]) - m) * iv * g1.z + b1.z);
    o[7] = f2bf((bf2f((unsigned short)t[7]) - m) * iv * g1.w + b1.w);
    *(u16x8*)&Ts[l][f8] = o;
  }
  __syncthreads();
#pragma unroll
  for (int it = 0; it < 8; ++it) {
    int idx = it * 256 + tid;
    int ll = idx >> 6, f8 = (idx & 63) * 8;
    u16x8 v = *(const u16x8*)&Ts[ll][f8];
    *(u16x8*)(o16 + ((size_t)b * 512 + l0 + ll) * 512 + f8) = v;
  }
}

// ---------- fused LayerNorm bf16 -> bf16 ----------
__global__ __launch_bounds__(256) void ln_k(const unsigned short* __restrict__ in,
                                            const float* __restrict__ g,
                                            const float* __restrict__ bq,
                                            unsigned short* __restrict__ o16) {
  int row = blockIdx.x * 4 + (threadIdx.x >> 6);
  int lane = threadIdx.x & 63;
  u16x8 u = *(const u16x8*)(in + (size_t)row * 512 + lane * 8);
  float v[8];
#pragma unroll
  for (int j = 0; j < 8; ++j) v[j] = bf2f(u[j]);
  float s1 = 0.f, s2 = 0.f;
#pragma unroll
  for (int j = 0; j < 8; ++j) { s1 += v[j]; s2 += v[j] * v[j]; }
#pragma unroll
  for (int off = 1; off < 64; off <<= 1) { s1 += __shfl_xor(s1, off); s2 += __shfl_xor(s2, off); }
  float m = s1 * (1.f / 512.f);
  float var = fmaxf(s2 * (1.f / 512.f) - m * m, 0.f);
  float iv = 1.f / sqrtf(var + EPS_LN);
  float4 g0 = *(const float4*)(g + lane * 8);
  float4 g1 = *(const float4*)(g + lane * 8 + 4);
  float4 b0 = *(const float4*)(bq + lane * 8);
  float4 b1 = *(const float4*)(bq + lane * 8 + 4);
  u16x8 o;
  o[0] = f2bf((v[0] - m) * iv * g0.x + b0.x);
  o[1] = f2bf((v[1] - m) * iv * g0.y + b0.y);
  o[2] = f2bf((v[2] - m) * iv * g0.z + b0.z);
  o[3] = f2bf((v[3] - m) * iv * g0.w + b0.w);
  o[4] = f2bf((v[4] - m) * iv * g1.x + b1.x);
  o[5] = f2bf((v[5] - m) * iv * g1.y + b1.y);
  o[6] = f2bf((v[6] - m) * iv * g1.z + b1.z);
  o[7] = f2bf((v[7] - m) * iv * g1.w + b1.w);
  *(u16x8*)(o16 + (size_t)row * 512 + lane * 8) = o;
}

// ---------- convert 8 (512x512) fp32 weights -> bf16 packed ----------
__global__ __launch_bounds__(256) void wconv_k(const float* w0, const float* w1,
                                               const float* w2, const float* w3,
                                               const float* w4, const float* w5,
                                               const float* w6, const float* w7,
                                               unsigned short* __restrict__ out) {
  const float* srcs[8] = {w0, w1, w2, w3, w4, w5, w6, w7};
  const float* s = srcs[blockIdx.y];
  size_t idx = (size_t)blockIdx.x * 2048 + threadIdx.x * 8;
  float4 v0 = *(const float4*)(s + idx);
  float4 v1 = *(const float4*)(s + idx + 4);
  u16x8 o;
  o[0] = f2bf(v0.x); o[1] = f2bf(v0.y); o[2] = f2bf(v0.z); o[3] = f2bf(v0.w);
  o[4] = f2bf(v1.x); o[5] = f2bf(v1.y); o[6] = f2bf(v1.z); o[7] = f2bf(v1.w);
  *(u16x8*)(out + (size_t)blockIdx.y * 262144 + idx) = o;
}

// ---------- wave-private staging: 64 rows x 32 k strip, 4 x gload16 ----------
// LDS linear [64][32] per strip; source k-slot pre-swizzled: s ^ ((lr>>1)&3).
__device__ __forceinline__ void stage_strip(const unsigned short* __restrict__ src,
                                            unsigned short* dst, int lane) {
  const int r4 = lane >> 2;          // row within 16
  const int s4 = lane & 3;           // phys 16B slot written
#pragma unroll
  for (int c = 0; c < 4; ++c) {
    int lr = c * 16 + r4;
    int gs = s4 ^ ((lr >> 1) & 3);
    gload16(src + (size_t)lr * 512 + gs * 8, dst + c * 16 * 32);
  }
}

// ---------- wave-private double-buffered GEMM core: BK=32, 16 K-steps,
//            counted vmcnt(8), no barriers in loop ----------
__device__ __forceinline__ void gemm_core_wp(const unsigned short* __restrict__ A,
                                             const unsigned short* __restrict__ W,
                                             unsigned short* smem,     // 32768 ushorts
                                             f32x4 (&acc)[4][4],
                                             int m0, int wrow, int tid) {
  const int w = tid >> 6, lane = tid & 63;
  const int wr = w >> 1, wc = w & 1;
  const unsigned short* Asrc = A + (size_t)(m0 + wr * 64) * 512;
  const unsigned short* Wsrc = W + (size_t)(wrow + wc * 64) * 512;
  unsigned short* reg0 = smem + w * 8192;     // buf0: A[0,2048) B[2048,4096)
  unsigned short* reg1 = reg0 + 4096;         // buf1
  const int lane15 = lane & 15, ks = lane >> 4;
  const int phys = ks ^ ((lane15 >> 1) & 3);

  stage_strip(Asrc, reg0, lane);
  stage_strip(Wsrc, reg0 + 2048, lane);
  stage_strip(Asrc + 32, reg1, lane);
  stage_strip(Wsrc + 32, reg1 + 2048, lane);
  for (int t = 0; t < 16; ++t) {
    unsigned short* buf = (t & 1) ? reg1 : reg0;
    if (t < 15) { asm volatile("s_waitcnt vmcnt(8)" ::: "memory"); }
    else        { asm volatile("s_waitcnt vmcnt(0)" ::: "memory"); }
    bf16x8 fa[4], fb[4];
#pragma unroll
    for (int i = 0; i < 4; ++i) {
      int lr = i * 16 + lane15;
      fa[i] = *(const bf16x8*)&buf[lr * 32 + phys * 8];
      fb[i] = *(const bf16x8*)&buf[2048 + lr * 32 + phys * 8];
    }
    asm volatile("s_waitcnt lgkmcnt(0)" ::: "memory");
    if (t < 14) {
      stage_strip(Asrc + (t + 2) * 32, buf, lane);
      stage_strip(Wsrc + (t + 2) * 32, buf + 2048, lane);
    }
#pragma unroll
    for (int i = 0; i < 4; ++i)
#pragma unroll
      for (int j = 0; j < 4; ++j)
        acc[i][j] = __builtin_amdgcn_mfma_f32_16x16x32_bf16(fa[i], fb[j], acc[i][j], 0, 0, 0);
  }
  __syncthreads();   // all waves done with K-loop LDS before epilogue reuses it
}

// ---------- templated epilogue (Wo GEMMs) ----------
template <int TRANS, int ACT, int RES>
__device__ __forceinline__ void gemm_epilogue(f32x4 (&acc)[4][4],
                                              unsigned short* Cs,   // [128][136]
                                              const float* __restrict__ bias,
                                              const unsigned short* __restrict__ resid,
                                              unsigned short* __restrict__ out,
                                              int m0, int n0, int tid) {
  const int w = tid >> 6, lane = tid & 63;
  const int wr = w >> 1, wc = w & 1;
  const int ro = (lane >> 4) * 4, c16 = lane & 15;
#pragma unroll
  for (int j = 0; j < 4; ++j) {
    int nl = wc * 64 + j * 16 + c16;
    float bi = bias[n0 + nl];
#pragma unroll
    for (int i = 0; i < 4; ++i) {
      int ml = wr * 64 + i * 16 + ro;
#pragma unroll
      for (int r = 0; r < 4; ++r) {
        float v = acc[i][j][r] + bi;
        if constexpr (ACT) v = (v > 0.f) ? v + 1.f : __expf(v);
        if constexpr (TRANS) Cs[nl * 136 + ml + r] = f2bf(v);
        else                 Cs[(ml + r) * 136 + nl] = f2bf(v);
      }
    }
  }
  __syncthreads();
  size_t rowbase; int colbase;
  if constexpr (TRANS) { rowbase = (size_t)((m0 >> 9) * 512 + n0); colbase = m0 & 511; }
  else                 { rowbase = (size_t)m0; colbase = n0; }
#pragma unroll
  for (int c = 0; c < 8; ++c) {
    int idx = c * 256 + tid;
    int rr = idx >> 4, c8 = (idx & 15) * 8;
    u16x8 v = *(const u16x8*)&Cs[rr * 136 + c8];
    size_t gaddr = (rowbase + rr) * 512 + colbase + c8;
    if constexpr (RES) {
      u16x8 rv = *(const u16x8*)(resid + gaddr);
#pragma unroll
      for (int q = 0; q < 8; ++q) v[q] = f2bf(bf2f(v[q]) + bf2f(rv[q]));
    }
    *(u16x8*)(out + gaddr) = v;
  }
}

// ---------- standard GEMM dispatch (Wo): 1D grid 1024, XCD-chunked, n-inner ----------
template <int TRANS, int ACT, int RES>
__global__ __launch_bounds__(256) void gemm_std_k(const unsigned short* __restrict__ A,
                                                  const unsigned short* __restrict__ W,
                                                  const float* __restrict__ bias,
                                                  const unsigned short* __restrict__ resid,
                                                  unsigned short* __restrict__ out) {
  __shared__ unsigned short smem[32768] __attribute__((aligned(16)));  // 64 KB
  const int tid = threadIdx.x;
  const int bid = blockIdx.x;
  const int nb = (bid & 7) * 128 + (bid >> 3);   // bijective, 1024 % 8 == 0
  const int m0 = (nb >> 2) * 128;
  const int n0 = (nb & 3) * 128;
  f32x4 acc[4][4] = {};
  gemm_core_wp(A, W, smem, acc, m0, n0, tid);
  gemm_epilogue<TRANS, ACT, RES>(acc, smem, bias, resid, out, m0, n0, tid);
}

// ---------- fused QKV GEMM: grid 3072, 12 n-tiles per A-panel adjacent ----------
__global__ __launch_bounds__(256) void gemm_qkv3_k(const unsigned short* __restrict__ A,
                                                   const unsigned short* __restrict__ Wqkv,
                                                   const float* __restrict__ bq,
                                                   const float* __restrict__ bk,
                                                   const float* __restrict__ bv,
                                                   unsigned short* __restrict__ Q,
                                                   unsigned short* __restrict__ K,
                                                   unsigned short* __restrict__ V) {
  __shared__ unsigned short smem[32768] __attribute__((aligned(16)));  // 64 KB
  const int tid = threadIdx.x;
  const unsigned int bid = blockIdx.x;
  const unsigned int nb = (bid & 7) * 384 + (bid >> 3);  // bijective, 3072 % 8 == 0
  const int mi = nb / 12, ni = nb % 12;                  // 12 consecutive share A-panel
  const int m0 = mi * 128;
  const int mat = ni >> 2;                               // 0=Q, 1=K, 2=V
  const int n0 = (ni & 3) * 128;
  f32x4 acc[4][4] = {};
  gemm_core_wp(A, Wqkv, smem, acc, m0, mat * 512 + n0, tid);

  const float* bias = (mat == 0) ? bq : (mat == 1) ? bk : bv;
  unsigned short* out = (mat == 0) ? Q : (mat == 1) ? K : V;
  const bool trans = (mat > 0);
  const bool act = (mat < 2);

  const int w = tid >> 6, lane = tid & 63;
  const int wr = w >> 1, wc = w & 1;
  const int ro = (lane >> 4) * 4, c16 = lane & 15;
  unsigned short* Cs = smem;
#pragma unroll
  for (int j = 0; j < 4; ++j) {
    int nl = wc * 64 + j * 16 + c16;
    float bi = bias[n0 + nl];
#pragma unroll
    for (int i = 0; i < 4; ++i) {
      int ml = wr * 64 + i * 16 + ro;
#pragma unroll
      for (int r = 0; r < 4; ++r) {
        float v = acc[i][j][r] + bi;
        if (act) v = (v > 0.f) ? v + 1.f : __expf(v);
        int row = trans ? nl : (ml + r);
        int col = trans ? (ml + r) : nl;
        Cs[row * 136 + col] = f2bf(v);
      }
    }
  }
  __syncthreads();
  size_t rowbase = trans ? (size_t)((m0 >> 9) * 512 + n0) : (size_t)m0;
  int colbase = trans ? (m0 & 511) : n0;
#pragma unroll
  for (int c = 0; c < 8; ++c) {
    int idx = c * 256 + tid;
    int rr = idx >> 4, c8 = (idx & 15) * 8;
    u16x8 v = *(const u16x8*)&Cs[rr * 136 + c8];
    *(u16x8*)(out + (rowbase + rr) * 512 + colbase + c8) = v;
  }
}

// ---------- KVT[e][d] = sum_n VT[e][n]*KT[d][n]; Z via MFMA-with-ones ----------
__global__ __launch_bounds__(256) void kv_mfma_k(const unsigned short* __restrict__ KT,
                                                 const unsigned short* __restrict__ VT,
                                                 unsigned short* __restrict__ KVTo,
                                                 float* __restrict__ Zo) {
  int bh = blockIdx.x;
  int tid = threadIdx.x, w = tid >> 6, lane = tid & 63;
  int r16 = lane & 15, g = lane >> 4;
  const unsigned short* vb = VT + ((size_t)bh * 64 + w * 16 + r16) * 512 + g * 8;
  const unsigned short* kb = KT + ((size_t)bh * 64 + r16) * 512 + g * 8;
  const short ob = (short)0x3F80;                 // bf16 1.0
  const bf16x8 onesf = {ob, ob, ob, ob, ob, ob, ob, ob};
  f32x4 acc[4] = {};
  f32x4 zacc[4] = {};
  for (int n0 = 0; n0 < 512; n0 += 32) {
    bf16x8 vf = *(const bf16x8*)(vb + n0);
#pragma unroll
    for (int j = 0; j < 4; ++j) {
      bf16x8 kf = *(const bf16x8*)(kb + (size_t)j * 16 * 512 + n0);
      acc[j] = __builtin_amdgcn_mfma_f32_16x16x32_bf16(vf, kf, acc[j], 0, 0, 0);
      zacc[j] = __builtin_amdgcn_mfma_f32_16x16x32_bf16(onesf, kf, zacc[j], 0, 0, 0);
    }
  }
  int e = w * 16 + g * 4;
  unsigned short* kvo = KVTo + (size_t)bh * 4096;
#pragma unroll
  for (int j = 0; j < 4; ++j)
#pragma unroll
    for (int r = 0; r < 4; ++r)
      kvo[(size_t)(e + r) * 64 + j * 16 + r16] = f2bf(acc[j][r]);
  if (w == 0 && g == 0) {
#pragma unroll
    for (int j = 0; j < 4; ++j) Zo[(size_t)bh * 64 + j * 16 + r16] = zacc[j][0];
  }
}

// ---------- O = (Q @ KVT^T)/(Q·Z+eps), in-place over Q ----------
__global__ __launch_bounds__(512) void attn_mfma_k(unsigned short* __restrict__ Q16,
                                                   const unsigned short* __restrict__ KVT,
                                                   const float* __restrict__ Z) {
  __shared__ unsigned short kvs[32768] __attribute__((aligned(16)));
  __shared__ float Zs[512];
  int tid = threadIdx.x;
  int b = blockIdx.x >> 2;
  int m0 = blockIdx.x * 128;
  const unsigned short* kg = KVT + (size_t)b * 32768;
#pragma unroll
  for (int t = 0; t < 8; ++t) {
    int c = tid + t * 512;
    int e = (c >> 3) & 63;
    u16x8 v = *(const u16x8*)(kg + (size_t)c * 8);
    *(u16x8*)((char*)kvs + ((c * 16) ^ ((e & 7) << 4))) = v;
  }
  Zs[tid] = Z[(size_t)b * 512 + tid];
  __syncthreads();

  int w = tid >> 6, lane = tid & 63;
  int r16 = lane & 15, g = lane >> 4;
  unsigned short* qrow = Q16 + (size_t)(m0 + w * 16 + r16) * 512;
  int orow0 = m0 + w * 16 + g * 4;

  for (int h = 0; h < 8; ++h) {
    bf16x8 q0 = *(const bf16x8*)(qrow + h * 64 + g * 8);
    bf16x8 q1 = *(const bf16x8*)(qrow + h * 64 + 32 + g * 8);
    const float* zh = Zs + h * 64;
    float np = 0.f;
#pragma unroll
    for (int q = 0; q < 8; ++q) np = fmaf(bf2f((unsigned short)q0[q]), zh[g * 8 + q], np);
#pragma unroll
    for (int q = 0; q < 8; ++q) np = fmaf(bf2f((unsigned short)q1[q]), zh[32 + g * 8 + q], np);

    f32x4 acc[4] = {};
#pragma unroll
    for (int j = 0; j < 4; ++j) {
      int e = j * 16 + r16;
      int byte0 = h * 8192 + e * 128;
      int sw = (e & 7) << 4;
      bf16x8 k0 = *(const bf16x8*)((char*)kvs + ((byte0 + g * 16) ^ sw));
      bf16x8 k1 = *(const bf16x8*)((char*)kvs + ((byte0 + 64 + g * 16) ^ sw));
      acc[j] = __builtin_amdgcn_mfma_f32_16x16x32_bf16(q0, k0, acc[j], 0, 0, 0);
      acc[j] = __builtin_amdgcn_mfma_f32_16x16x32_bf16(q1, k1, acc[j], 0, 0, 0);
    }
    np += __shfl_xor(np, 16);
    np += __shfl_xor(np, 32);
    float inv = 1.f / (np + EPS_ATTN);
    float inv4[4];
#pragma unroll
    for (int r = 0; r < 4; ++r) inv4[r] = __shfl(inv, g * 4 + r);
#pragma unroll
    for (int j = 0; j < 4; ++j)
#pragma unroll
      for (int r = 0; r < 4; ++r)
        Q16[(size_t)(orow0 + r) * 512 + h * 64 + j * 16 + r16] = f2bf(acc[j][r] * inv4[r]);
  }
}

// ---------- feat_linear via MFMA: per f, Y[b,p] = sum_l h3[b,f,l]*Wlin[f,p,l] ----------
__global__ __launch_bounds__(256) void feat_linear_k(const unsigned short* __restrict__ h3,
                                                     const float* __restrict__ Wlin,
                                                     const float* __restrict__ blin,
                                                     float* __restrict__ Y) {
  __shared__ unsigned short As[64 * 64] __attribute__((aligned(16)));   // 8 KB
  __shared__ unsigned short Bs[96 * 64] __attribute__((aligned(16)));   // 12 KB
  const int f = blockIdx.x;
  const int tid = threadIdx.x;
  const int w = tid >> 6, lane = tid & 63;
  const int r16 = lane & 15, g = lane >> 4;
  const int r8 = lane >> 3, s8 = lane & 7, gs = s8 ^ r8;

  f32x4 acc[6] = {};
  for (int k0 = 0; k0 < 512; k0 += 64) {
#pragma unroll
    for (int c = 0; c < 2; ++c) {
      int row = w * 16 + c * 8 + r8;
      gload16(h3 + ((size_t)row * 512 + f) * 512 + k0 + gs * 8,
              As + (w * 16 + c * 8) * 64);
    }
#pragma unroll
    for (int it = 0; it < 3; ++it) {
      int idx = it * 256 + tid;
      int pp = idx >> 3, sl = idx & 7;
      const float* src = Wlin + ((size_t)f * 96 + pp) * 512 + k0 + sl * 8;
      float4 v0 = *(const float4*)src;
      float4 v1 = *(const float4*)(src + 4);
      u16x8 o;
      o[0] = f2bf(v0.x); o[1] = f2bf(v0.y); o[2] = f2bf(v0.z); o[3] = f2bf(v0.w);
      o[4] = f2bf(v1.x); o[5] = f2bf(v1.y); o[6] = f2bf(v1.z); o[7] = f2bf(v1.w);
      *(u16x8*)&Bs[pp * 64 + (sl ^ (pp & 7)) * 8] = o;
    }
    __syncthreads();
#pragma unroll
    for (int s = 0; s < 2; ++s) {
      int arow = w * 16 + r16;
      bf16x8 fa = *(const bf16x8*)&As[arow * 64 + (((s * 4 + g) ^ (arow & 7)) * 8)];
#pragma unroll
      for (int n = 0; n < 6; ++n) {
        int brow = n * 16 + r16;
        bf16x8 fb = *(const bf16x8*)&Bs[brow * 64 + (((s * 4 + g) ^ (brow & 7)) * 8)];
        acc[n] = __builtin_amdgcn_mfma_f32_16x16x32_bf16(fa, fb, acc[n], 0, 0, 0);
      }
    }
    __syncthreads();
  }
  const int b0 = w * 16 + g * 4;
#pragma unroll
  for (int n = 0; n < 6; ++n) {
    float bi = blin[f * 96 + n * 16 + r16];
#pragma unroll
    for (int r = 0; r < 4; ++r)
      Y[((size_t)(b0 + r) * 512 + f) * 96 + n * 16 + r16] = acc[n][r] + bi;
  }
}

// ---------- final: denorm + projector ----------
__global__ __launch_bounds__(256) void final_out_k(const float* __restrict__ Y,
                                                   const float* __restrict__ meanb,
                                                   const float* __restrict__ stdb,
                                                   const float* __restrict__ rg,
                                                   const float* __restrict__ rb,
                                                   const float* __restrict__ Wproj,
                                                   const float* __restrict__ bproj,
                                                   float* __restrict__ out) {
  int b = blockIdx.x;
  __shared__ float cs[512];
  __shared__ float kred[4];
  int t = threadIdx.x;
  float kpart = 0.f;
  for (int f = t; f < 512; f += 256) {
    float sd = stdb[b * 512 + f], mn = meanb[b * 512 + f];
    float g = rg[f], rbv = rb[f], wp = Wproj[f];
    float c = wp * sd / g;
    cs[f] = c;
    kpart += wp * mn - c * rbv;
  }
#pragma unroll
  for (int off = 32; off; off >>= 1) kpart += __shfl_down(kpart, off);
  int wid = t >> 6, lane = t & 63;
  if (lane == 0) kred[wid] = kpart;
  __syncthreads();
  float K = kred[0] + kred[1] + kred[2] + kred[3] + bproj[0];
  if (t < 96) {
    float acc = 0.f;
    for (int f = 0; f < 512; ++f) acc = fmaf(cs[f], Y[((size_t)b * 512 + f) * 96 + t], acc);
    out[b * 96 + t] = acc + K;
  }
}

extern "C" void kernel_launch(void* const* d_in, const int* in_sizes, int n_in,
                              void* d_out, int out_size, void* d_ws, size_t ws_size,
                              hipStream_t stream) {
  const float* x    = (const float*)d_in[0];
  const float* rg   = (const float*)d_in[1];
  const float* rb   = (const float*)d_in[2];
  const float* n1g  = (const float*)d_in[3];
  const float* n1b  = (const float*)d_in[4];
  const float* n2g  = (const float*)d_in[5];
  const float* n2b  = (const float*)d_in[6];
  const float* tWq  = (const float*)d_in[7];
  const float* tbq  = (const float*)d_in[8];
  const float* tWk  = (const float*)d_in[9];
  const float* tbk  = (const float*)d_in[10];
  const float* tWv  = (const float*)d_in[11];
  const float* tbv  = (const float*)d_in[12];
  const float* tWo  = (const float*)d_in[13];
  const float* tbo  = (const float*)d_in[14];
  const float* fWq  = (const float*)d_in[15];
  const float* fbq  = (const float*)d_in[16];
  const float* fWk  = (const float*)d_in[17];
  const float* fbk  = (const float*)d_in[18];
  const float* fWv  = (const float*)d_in[19];
  const float* fbv  = (const float*)d_in[20];
  const float* fWo  = (const float*)d_in[21];
  const float* fbo  = (const float*)d_in[22];
  const float* Wlin = (const float*)d_in[23];
  const float* blin = (const float*)d_in[24];
  const float* Wprj = (const float*)d_in[25];
  const float* bprj = (const float*)d_in[26];
  float* out = (float*)d_out;

  const size_t SZ = (size_t)64 * 512 * 512;
  char* p = (char*)d_ws;
  unsigned short* xn  = (unsigned short*)p; p += SZ * 2;   // RevIN'd x, (B,F,L)
  unsigned short* h2  = (unsigned short*)p; p += SZ * 2;   // (B,F,L)
  unsigned short* h3  = (unsigned short*)p; p += SZ * 2;   // (B,F,L)
  unsigned short* abf = (unsigned short*)p; p += SZ * 2;   // LN out / ybuf alias
  unsigned short* q16 = (unsigned short*)p; p += SZ * 2;
  unsigned short* k16 = (unsigned short*)p; p += SZ * 2;
  unsigned short* v16 = (unsigned short*)p; p += SZ * 2;
  unsigned short* wbf = (unsigned short*)p; p += (size_t)8 * 262144 * 2;
  unsigned short* kvt = (unsigned short*)p; p += (size_t)512 * 4096 * 2;
  float* z     = (float*)p;         p += (size_t)512 * 64 * 4;
  float* meanb = (float*)p;         p += 32768 * 4;
  float* stdb  = (float*)p;         p += 32768 * 4;
  float* ybuf  = (float*)abf;       // abf dead before feat_linear

  wconv_k<<<dim3(128, 8), 256, 0, stream>>>(tWq, tWk, tWv, tWo, fWq, fWk, fWv, fWo, wbf);
  revin_xn_k<<<8192, 256, 0, stream>>>(x, rg, rb, meanb, stdb, xn);

  // --- temporal attention block (tokens = l, dim = F) ---
  tln_k<<<dim3(16, 64), 256, 0, stream>>>(xn, n1g, n1b, abf);
  gemm_qkv3_k<<<3072, 256, 0, stream>>>(abf, wbf, tbq, tbk, tbv, q16, k16, v16);
  kv_mfma_k<<<512, 256, 0, stream>>>(k16, v16, kvt, z);
  attn_mfma_k<<<256, 512, 0, stream>>>(q16, kvt, z);
  gemm_std_k<1, 0, 1><<<1024, 256, 0, stream>>>(q16, wbf + 3 * 262144, tbo, xn, h2);

  // --- feature attention block (tokens = f, dim = L) ---
  ln_k<<<8192, 256, 0, stream>>>(h2, n2g, n2b, abf);
  gemm_qkv3_k<<<3072, 256, 0, stream>>>(abf, wbf + 4 * 262144, fbq, fbk, fbv, q16, k16, v16);
  kv_mfma_k<<<512, 256, 0, stream>>>(k16, v16, kvt, z);
  attn_mfma_k<<<256, 512, 0, stream>>>(q16, kvt, z);
  gemm_std_k<0, 0, 1><<<1024, 256, 0, stream>>>(q16, wbf + 7 * 262144, fbo, h2, h3);

  // tail
  feat_linear_k<<<512, 256, 0, stream>>>(h3, Wlin, blin, ybuf);
  final_out_k<<<64, 256, 0, stream>>>(ybuf, meanb, stdb, rg, rb, Wprj, bprj, out);
}

// Round 12
// 398.477 us; speedup vs baseline: 1.8142x; 1.0811x over previous
//
#include <hip/hip_runtime.h>
#include <hip/hip_bf16.h>
#include <cstdint>
#include <cstddef>

// LinearCrypto MI355X round 12: 256x256 8-wave GEMM with counted vmcnt(8)
// pipeline (guide's 8-phase template adapted to K=512), raw s_barrier.
// Rest = round 9 (381 us). B=64, F=512, L=512, P=96, H=8, M=32768.

#define EPS_ATTN 1e-6f
#define EPS_LN   1e-5f
#define EPS_REVIN 1e-5f

typedef __attribute__((ext_vector_type(8))) short bf16x8;
typedef __attribute__((ext_vector_type(4))) float f32x4;
typedef __attribute__((ext_vector_type(8))) unsigned short u16x8;

__device__ __forceinline__ float bf2f(unsigned short u) {
  unsigned int x = ((unsigned int)u) << 16;
  return __builtin_bit_cast(float, x);
}
__device__ __forceinline__ unsigned short f2bf(float f) {
  __hip_bfloat16 h = __float2bfloat16(f);
  return __builtin_bit_cast(unsigned short, h);
}
__device__ __forceinline__ void gload16(const void* g, void* l) {
  __builtin_amdgcn_global_load_lds(
      (const __attribute__((address_space(1))) void*)g,
      (__attribute__((address_space(3))) void*)l, 16, 0, 0);
}

// ---------- RevIN stats + normalized bf16 copy xn (B,F,L) ----------
__global__ __launch_bounds__(256) void revin_xn_k(const float* __restrict__ x,
                                                  const float* __restrict__ rg,
                                                  const float* __restrict__ rb,
                                                  float* __restrict__ meanb,
                                                  float* __restrict__ stdb,
                                                  unsigned short* __restrict__ xn) {
  int wid = threadIdx.x >> 6, lane = threadIdx.x & 63;
  int row = blockIdx.x * 4 + wid;               // b*512 + f
  const float* xr = x + (size_t)row * 512 + lane * 8;
  float4 a = *(const float4*)xr;
  float4 c = *(const float4*)(xr + 4);
  float s1 = a.x + a.y + a.z + a.w + c.x + c.y + c.z + c.w;
  float s2 = a.x * a.x + a.y * a.y + a.z * a.z + a.w * a.w +
             c.x * c.x + c.y * c.y + c.z * c.z + c.w * c.w;
#pragma unroll
  for (int off = 1; off < 64; off <<= 1) { s1 += __shfl_xor(s1, off); s2 += __shfl_xor(s2, off); }
  float m = s1 * (1.f / 512.f);
  float var = fmaxf((s2 - 512.f * m * m) * (1.f / 511.f), 0.f);
  float sd = sqrtf(var) + EPS_REVIN;
  int f = row & 511;
  float sc = rg[f] / sd;
  float of = rb[f] - m * sc;
  u16x8 o;
  o[0] = f2bf(a.x * sc + of); o[1] = f2bf(a.y * sc + of);
  o[2] = f2bf(a.z * sc + of); o[3] = f2bf(a.w * sc + of);
  o[4] = f2bf(c.x * sc + of); o[5] = f2bf(c.y * sc + of);
  o[6] = f2bf(c.z * sc + of); o[7] = f2bf(c.w * sc + of);
  *(u16x8*)(xn + (size_t)row * 512 + lane * 8) = o;
  if (lane == 0) { meanb[row] = m; stdb[row] = sd; }
}

// ---------- fused transpose + LayerNorm: xn (B,F,L) -> abf (B,L,F) LN'd ----------
__global__ __launch_bounds__(256) void tln_k(const unsigned short* __restrict__ xn,
                                             const float* __restrict__ g,
                                             const float* __restrict__ bq,
                                             unsigned short* __restrict__ o16) {
  __shared__ unsigned short Ts[32][528] __attribute__((aligned(16)));
  const int b = blockIdx.y, l0 = blockIdx.x * 32;
  const int tid = threadIdx.x;
#pragma unroll
  for (int it = 0; it < 8; ++it) {
    int idx = it * 256 + tid;
    int f = idx >> 2, lc = (idx & 3) * 8;
    u16x8 v = *(const u16x8*)(xn + ((size_t)b * 512 + f) * 512 + l0 + lc);
#pragma unroll
    for (int j = 0; j < 8; ++j) Ts[lc + j][f] = v[j];
  }
  __syncthreads();
  const int l = tid >> 3, q = tid & 7;
  float s1 = 0.f, s2 = 0.f;
#pragma unroll
  for (int i = 0; i < 8; ++i) {
    int c = (i + q) & 7;
    bf16x8 t = *(const bf16x8*)&Ts[l][q * 64 + c * 8];
#pragma unroll
    for (int j = 0; j < 8; ++j) {
      float x = bf2f((unsigned short)t[j]);
      s1 += x; s2 += x * x;
    }
  }
#pragma unroll
  for (int off = 1; off < 8; off <<= 1) { s1 += __shfl_xor(s1, off); s2 += __shfl_xor(s2, off); }
  float m = s1 * (1.f / 512.f);
  float var = fmaxf(s2 * (1.f / 512.f) - m * m, 0.f);
  float iv = 1.f / sqrtf(var + EPS_LN);
#pragma unroll
  for (int i = 0; i < 8; ++i) {
    int c = (i + q) & 7;
    int f8 = q * 64 + c * 8;
    bf16x8 t = *(const bf16x8*)&Ts[l][f8];
    float4 g0 = *(const float4*)(g + f8);
    float4 g1 = *(const float4*)(g + f8 + 4);
    float4 b0 = *(const float4*)(bq + f8);
    float4 b1 = *(const float4*)(bq + f8 + 4);
    u16x8 o;
    o[0] = f2bf((bf2f((unsigned short)t[0]) - m) * iv * g0.x + b0.x);
    o[1] = f2bf((bf2f((unsigned short)t[1]) - m) * iv * g0.y + b0.y);
    o[2] = f2bf((bf2f((unsigned short)t[2]) - m) * iv * g0.z + b0.z);
    o[3] = f2bf((bf2f((unsigned short)t[3]) - m) * iv * g0.w + b0.w);
    o[4] = f2bf((bf2f((unsigned short)t[4]) - m) * iv * g1.x + b1.x);
    o[5] = f2bf((bf2f((unsigned short)t[5]) - m) * iv * g1.y + b1.y);
    o[6] = f2bf((bf2f((unsigned short)t[6]) - m) * iv * g1.z + b1.z);
    o[7] = f2bf((bf2f((unsigned short)t[7]) - m) * iv * g1.w + b1.w);
    *(u16x8*)&Ts[l][f8] = o;
  }
  __syncthreads();
#pragma unroll
  for (int it = 0; it < 8; ++it) {
    int idx = it * 256 + tid;
    int ll = idx >> 6, f8 = (idx & 63) * 8;
    u16x8 v = *(const u16x8*)&Ts[ll][f8];
    *(u16x8*)(o16 + ((size_t)b * 512 + l0 + ll) * 512 + f8) = v;
  }
}

// ---------- fused LayerNorm bf16 -> bf16 ----------
__global__ __launch_bounds__(256) void ln_k(const unsigned short* __restrict__ in,
                                            const float* __restrict__ g,
                                            const float* __restrict__ bq,
                                            unsigned short* __restrict__ o16) {
  int row = blockIdx.x * 4 + (threadIdx.x >> 6);
  int lane = threadIdx.x & 63;
  u16x8 u = *(const u16x8*)(in + (size_t)row * 512 + lane * 8);
  float v[8];
#pragma unroll
  for (int j = 0; j < 8; ++j) v[j] = bf2f(u[j]);
  float s1 = 0.f, s2 = 0.f;
#pragma unroll
  for (int j = 0; j < 8; ++j) { s1 += v[j]; s2 += v[j] * v[j]; }
#pragma unroll
  for (int off = 1; off < 64; off <<= 1) { s1 += __shfl_xor(s1, off); s2 += __shfl_xor(s2, off); }
  float m = s1 * (1.f / 512.f);
  float var = fmaxf(s2 * (1.f / 512.f) - m * m, 0.f);
  float iv = 1.f / sqrtf(var + EPS_LN);
  float4 g0 = *(const float4*)(g + lane * 8);
  float4 g1 = *(const float4*)(g + lane * 8 + 4);
  float4 b0 = *(const float4*)(bq + lane * 8);
  float4 b1 = *(const float4*)(bq + lane * 8 + 4);
  u16x8 o;
  o[0] = f2bf((v[0] - m) * iv * g0.x + b0.x);
  o[1] = f2bf((v[1] - m) * iv * g0.y + b0.y);
  o[2] = f2bf((v[2] - m) * iv * g0.z + b0.z);
  o[3] = f2bf((v[3] - m) * iv * g0.w + b0.w);
  o[4] = f2bf((v[4] - m) * iv * g1.x + b1.x);
  o[5] = f2bf((v[5] - m) * iv * g1.y + b1.y);
  o[6] = f2bf((v[6] - m) * iv * g1.z + b1.z);
  o[7] = f2bf((v[7] - m) * iv * g1.w + b1.w);
  *(u16x8*)(o16 + (size_t)row * 512 + lane * 8) = o;
}

// ---------- convert 8 (512x512) fp32 weights -> bf16 packed ----------
__global__ __launch_bounds__(256) void wconv_k(const float* w0, const float* w1,
                                               const float* w2, const float* w3,
                                               const float* w4, const float* w5,
                                               const float* w6, const float* w7,
                                               unsigned short* __restrict__ out) {
  const float* srcs[8] = {w0, w1, w2, w3, w4, w5, w6, w7};
  const float* s = srcs[blockIdx.y];
  size_t idx = (size_t)blockIdx.x * 2048 + threadIdx.x * 8;
  float4 v0 = *(const float4*)(s + idx);
  float4 v1 = *(const float4*)(s + idx + 4);
  u16x8 o;
  o[0] = f2bf(v0.x); o[1] = f2bf(v0.y); o[2] = f2bf(v0.z); o[3] = f2bf(v0.w);
  o[4] = f2bf(v1.x); o[5] = f2bf(v1.y); o[6] = f2bf(v1.z); o[7] = f2bf(v1.w);
  *(u16x8*)(out + (size_t)blockIdx.y * 262144 + idx) = o;
}

// ================= 256x256 8-wave GEMM core (counted-vmcnt pipeline) ========
// LDS: 2 buffers x (A 256x64 + B 256x64) bf16 = 128 KB; Cs alias 256x264.
// Stage: 8 gload16/thread/tile, linear LDS dest, inverse-swizzled source.
__device__ __forceinline__ void stage256(const unsigned short* __restrict__ Ag,
                                         const unsigned short* __restrict__ Wg,
                                         unsigned short* Ab, unsigned short* Bb,
                                         int tid, int kt) {
  const int koff = kt * 64;
#pragma unroll
  for (int c = 0; c < 4; ++c) {
    int idx = c * 512 + tid;
    int row = idx >> 3, slot = idx & 7;
    int gs = slot ^ (row & 7);
    gload16(Ag + (size_t)row * 512 + koff + gs * 8, Ab + idx * 8);
    gload16(Wg + (size_t)row * 512 + koff + gs * 8, Bb + idx * 8);
  }
}

__device__ __forceinline__ void gemm_core256(const unsigned short* __restrict__ A,
                                             const unsigned short* __restrict__ W,
                                             unsigned short* smem,
                                             f32x4 (&acc)[8][4],
                                             int m0, int wrow, int tid) {
  const int w = tid >> 6, lane = tid & 63;
  const int wr = w >> 2, wn = w & 3;
  const int r16 = lane & 15, g = lane >> 4;
  const int sw = r16 & 7;
  const unsigned short* Ag = A + (size_t)m0 * 512;
  const unsigned short* Wg = W + (size_t)wrow * 512;

  stage256(Ag, Wg, smem, smem + 16384, tid, 0);
  for (int kt = 0; kt < 8; ++kt) {
    const int p = kt & 1;
    unsigned short* Ab = smem + p * 32768;
    unsigned short* Bb = Ab + 16384;
    asm volatile("s_barrier" ::: "memory");      // everyone done reading buf p^1
    if (kt < 7) {
      unsigned short* An = smem + (p ^ 1) * 32768;
      stage256(Ag, Wg, An, An + 16384, tid, kt + 1);
      asm volatile("s_waitcnt vmcnt(8)" ::: "memory");  // tile kt landed; kt+1 in flight
    } else {
      asm volatile("s_waitcnt vmcnt(0)" ::: "memory");
    }
    asm volatile("s_barrier" ::: "memory");      // cross-wave visibility of tile kt
#pragma unroll
    for (int qm = 0; qm < 2; ++qm) {
      bf16x8 fa[4][2];
#pragma unroll
      for (int i4 = 0; i4 < 4; ++i4) {
        int row = wr * 128 + (qm * 4 + i4) * 16 + r16;
#pragma unroll
        for (int s = 0; s < 2; ++s)
          fa[i4][s] = *(const bf16x8*)&Ab[row * 64 + (((s * 4 + g) ^ sw) * 8)];
      }
#pragma unroll
      for (int qn = 0; qn < 2; ++qn) {
        bf16x8 fb[2][2];
#pragma unroll
        for (int j2 = 0; j2 < 2; ++j2) {
          int row = wn * 64 + (qn * 2 + j2) * 16 + r16;
#pragma unroll
          for (int s = 0; s < 2; ++s)
            fb[j2][s] = *(const bf16x8*)&Bb[row * 64 + (((s * 4 + g) ^ sw) * 8)];
        }
        __builtin_amdgcn_s_setprio(1);
#pragma unroll
        for (int i4 = 0; i4 < 4; ++i4)
#pragma unroll
          for (int j2 = 0; j2 < 2; ++j2)
#pragma unroll
            for (int s = 0; s < 2; ++s)
              acc[qm * 4 + i4][qn * 2 + j2] = __builtin_amdgcn_mfma_f32_16x16x32_bf16(
                  fa[i4][s], fb[j2][s], acc[qm * 4 + i4][qn * 2 + j2], 0, 0, 0);
        __builtin_amdgcn_s_setprio(0);
      }
    }
  }
  __syncthreads();   // drain + full barrier before Cs reuses LDS
}

// ---------- 256x256 epilogue: bias(+ELU) -> bf16 Cs (opt transpose) ->
//            streamed u16x8 writes (+bf16 residual) ----------
__device__ __forceinline__ void epi256(f32x4 (&acc)[8][4], unsigned short* Cs,
                                       const float* __restrict__ bias,
                                       const unsigned short* __restrict__ resid,
                                       unsigned short* __restrict__ out,
                                       int m0, int n0, int tid,
                                       bool trans, bool act, bool res) {
  const int w = tid >> 6, lane = tid & 63;
  const int wr = w >> 2, wn = w & 3;
  const int ro = (lane >> 4) * 4, c16 = lane & 15;
#pragma unroll
  for (int j = 0; j < 4; ++j) {
    int nl = wn * 64 + j * 16 + c16;
    float bi = bias[n0 + nl];
#pragma unroll
    for (int i = 0; i < 8; ++i) {
      int ml = wr * 128 + i * 16 + ro;
#pragma unroll
      for (int r = 0; r < 4; ++r) {
        float v = acc[i][j][r] + bi;
        if (act) v = (v > 0.f) ? v + 1.f : __expf(v);
        int row = trans ? nl : (ml + r);
        int col = trans ? (ml + r) : nl;
        Cs[row * 264 + col] = f2bf(v);
      }
    }
  }
  __syncthreads();
  size_t rowbase = trans ? (size_t)((m0 >> 9) * 512 + n0) : (size_t)m0;
  int colbase = trans ? (m0 & 511) : n0;
#pragma unroll
  for (int c = 0; c < 16; ++c) {
    int idx = c * 512 + tid;
    int rr = idx >> 5, c8 = (idx & 31) * 8;
    u16x8 v = *(const u16x8*)&Cs[rr * 264 + c8];
    size_t gaddr = (rowbase + rr) * 512 + colbase + c8;
    if (res) {
      u16x8 rv = *(const u16x8*)(resid + gaddr);
#pragma unroll
      for (int q = 0; q < 8; ++q) v[q] = f2bf(bf2f(v[q]) + bf2f(rv[q]));
    }
    *(u16x8*)(out + gaddr) = v;
  }
}

// ---------- fused QKV GEMM (256x256): grid 768, 6 n-tiles per A-panel ----------
__global__ __launch_bounds__(512, 2) void gemm_qkv256_k(
    const unsigned short* __restrict__ A,
    const unsigned short* __restrict__ Wqkv,
    const float* __restrict__ bq, const float* __restrict__ bk,
    const float* __restrict__ bv,
    unsigned short* __restrict__ Q, unsigned short* __restrict__ K,
    unsigned short* __restrict__ V) {
  __shared__ unsigned short smem[67584] __attribute__((aligned(16)));  // 132 KB
  const int tid = threadIdx.x;
  const unsigned int bid = blockIdx.x;
  const unsigned int nb = (bid & 7) * 96 + (bid >> 3);   // bijective, 768 % 8 == 0
  const int mi = nb / 6, ni = nb % 6;
  const int m0 = mi * 256;
  const int mat = ni >> 1;
  const int n0 = (ni & 1) * 256;
  f32x4 acc[8][4] = {};
  gemm_core256(A, Wqkv, smem, acc, m0, mat * 512 + n0, tid);
  const float* bias = (mat == 0) ? bq : (mat == 1) ? bk : bv;
  unsigned short* out = (mat == 0) ? Q : (mat == 1) ? K : V;
  epi256(acc, smem, bias, nullptr, out, m0, n0, tid, mat > 0, mat < 2, false);
}

// ---------- Wo GEMM (256x256): grid 256 ----------
template <int TRANS, int RES>
__global__ __launch_bounds__(512, 2) void gemm_std256_k(
    const unsigned short* __restrict__ A,
    const unsigned short* __restrict__ W,
    const float* __restrict__ bias,
    const unsigned short* __restrict__ resid,
    unsigned short* __restrict__ out) {
  __shared__ unsigned short smem[67584] __attribute__((aligned(16)));
  const int tid = threadIdx.x;
  const unsigned int bid = blockIdx.x;
  const unsigned int nb = (bid & 7) * 32 + (bid >> 3);   // bijective, 256 % 8 == 0
  const int m0 = (nb >> 1) * 256;
  const int n0 = (nb & 1) * 256;
  f32x4 acc[8][4] = {};
  gemm_core256(A, W, smem, acc, m0, n0, tid);
  epi256(acc, smem, bias, resid, out, m0, n0, tid, TRANS != 0, false, RES != 0);
}

// ---------- KVT[e][d] = sum_n VT[e][n]*KT[d][n]; Z via MFMA-with-ones ----------
__global__ __launch_bounds__(256) void kv_mfma_k(const unsigned short* __restrict__ KT,
                                                 const unsigned short* __restrict__ VT,
                                                 unsigned short* __restrict__ KVTo,
                                                 float* __restrict__ Zo) {
  int bh = blockIdx.x;
  int tid = threadIdx.x, w = tid >> 6, lane = tid & 63;
  int r16 = lane & 15, g = lane >> 4;
  const unsigned short* vb = VT + ((size_t)bh * 64 + w * 16 + r16) * 512 + g * 8;
  const unsigned short* kb = KT + ((size_t)bh * 64 + r16) * 512 + g * 8;
  const short ob = (short)0x3F80;                 // bf16 1.0
  const bf16x8 onesf = {ob, ob, ob, ob, ob, ob, ob, ob};
  f32x4 acc[4] = {};
  f32x4 zacc[4] = {};
  for (int n0 = 0; n0 < 512; n0 += 32) {
    bf16x8 vf = *(const bf16x8*)(vb + n0);
#pragma unroll
    for (int j = 0; j < 4; ++j) {
      bf16x8 kf = *(const bf16x8*)(kb + (size_t)j * 16 * 512 + n0);
      acc[j] = __builtin_amdgcn_mfma_f32_16x16x32_bf16(vf, kf, acc[j], 0, 0, 0);
      zacc[j] = __builtin_amdgcn_mfma_f32_16x16x32_bf16(onesf, kf, zacc[j], 0, 0, 0);
    }
  }
  int e = w * 16 + g * 4;
  unsigned short* kvo = KVTo + (size_t)bh * 4096;
#pragma unroll
  for (int j = 0; j < 4; ++j)
#pragma unroll
    for (int r = 0; r < 4; ++r)
      kvo[(size_t)(e + r) * 64 + j * 16 + r16] = f2bf(acc[j][r]);
  if (w == 0 && g == 0) {
#pragma unroll
    for (int j = 0; j < 4; ++j) Zo[(size_t)bh * 64 + j * 16 + r16] = zacc[j][0];
  }
}

// ---------- O = (Q @ KVT^T)/(Q·Z+eps), in-place over Q ----------
__global__ __launch_bounds__(512) void attn_mfma_k(unsigned short* __restrict__ Q16,
                                                   const unsigned short* __restrict__ KVT,
                                                   const float* __restrict__ Z) {
  __shared__ unsigned short kvs[32768] __attribute__((aligned(16)));
  __shared__ float Zs[512];
  int tid = threadIdx.x;
  int b = blockIdx.x >> 2;
  int m0 = blockIdx.x * 128;
  const unsigned short* kg = KVT + (size_t)b * 32768;
#pragma unroll
  for (int t = 0; t < 8; ++t) {
    int c = tid + t * 512;
    int e = (c >> 3) & 63;
    u16x8 v = *(const u16x8*)(kg + (size_t)c * 8);
    *(u16x8*)((char*)kvs + ((c * 16) ^ ((e & 7) << 4))) = v;
  }
  Zs[tid] = Z[(size_t)b * 512 + tid];
  __syncthreads();

  int w = tid >> 6, lane = tid & 63;
  int r16 = lane & 15, g = lane >> 4;
  unsigned short* qrow = Q16 + (size_t)(m0 + w * 16 + r16) * 512;
  int orow0 = m0 + w * 16 + g * 4;

  for (int h = 0; h < 8; ++h) {
    bf16x8 q0 = *(const bf16x8*)(qrow + h * 64 + g * 8);
    bf16x8 q1 = *(const bf16x8*)(qrow + h * 64 + 32 + g * 8);
    const float* zh = Zs + h * 64;
    float np = 0.f;
#pragma unroll
    for (int q = 0; q < 8; ++q) np = fmaf(bf2f((unsigned short)q0[q]), zh[g * 8 + q], np);
#pragma unroll
    for (int q = 0; q < 8; ++q) np = fmaf(bf2f((unsigned short)q1[q]), zh[32 + g * 8 + q], np);

    f32x4 acc[4] = {};
#pragma unroll
    for (int j = 0; j < 4; ++j) {
      int e = j * 16 + r16;
      int byte0 = h * 8192 + e * 128;
      int sw = (e & 7) << 4;
      bf16x8 k0 = *(const bf16x8*)((char*)kvs + ((byte0 + g * 16) ^ sw));
      bf16x8 k1 = *(const bf16x8*)((char*)kvs + ((byte0 + 64 + g * 16) ^ sw));
      acc[j] = __builtin_amdgcn_mfma_f32_16x16x32_bf16(q0, k0, acc[j], 0, 0, 0);
      acc[j] = __builtin_amdgcn_mfma_f32_16x16x32_bf16(q1, k1, acc[j], 0, 0, 0);
    }
    np += __shfl_xor(np, 16);
    np += __shfl_xor(np, 32);
    float inv = 1.f / (np + EPS_ATTN);
    float inv4[4];
#pragma unroll
    for (int r = 0; r < 4; ++r) inv4[r] = __shfl(inv, g * 4 + r);
#pragma unroll
    for (int j = 0; j < 4; ++j)
#pragma unroll
      for (int r = 0; r < 4; ++r)
        Q16[(size_t)(orow0 + r) * 512 + h * 64 + j * 16 + r16] = f2bf(acc[j][r] * inv4[r]);
  }
}

// ---------- feat_linear via MFMA ----------
__global__ __launch_bounds__(256) void feat_linear_k(const unsigned short* __restrict__ h3,
                                                     const float* __restrict__ Wlin,
                                                     const float* __restrict__ blin,
                                                     float* __restrict__ Y) {
  __shared__ unsigned short As[64 * 64] __attribute__((aligned(16)));
  __shared__ unsigned short Bs[96 * 64] __attribute__((aligned(16)));
  const int f = blockIdx.x;
  const int tid = threadIdx.x;
  const int w = tid >> 6, lane = tid & 63;
  const int r16 = lane & 15, g = lane >> 4;
  const int r8 = lane >> 3, s8 = lane & 7, gs = s8 ^ r8;

  f32x4 acc[6] = {};
  for (int k0 = 0; k0 < 512; k0 += 64) {
#pragma unroll
    for (int c = 0; c < 2; ++c) {
      int row = w * 16 + c * 8 + r8;
      gload16(h3 + ((size_t)row * 512 + f) * 512 + k0 + gs * 8,
              As + (w * 16 + c * 8) * 64);
    }
#pragma unroll
    for (int it = 0; it < 3; ++it) {
      int idx = it * 256 + tid;
      int pp = idx >> 3, sl = idx & 7;
      const float* src = Wlin + ((size_t)f * 96 + pp) * 512 + k0 + sl * 8;
      float4 v0 = *(const float4*)src;
      float4 v1 = *(const float4*)(src + 4);
      u16x8 o;
      o[0] = f2bf(v0.x); o[1] = f2bf(v0.y); o[2] = f2bf(v0.z); o[3] = f2bf(v0.w);
      o[4] = f2bf(v1.x); o[5] = f2bf(v1.y); o[6] = f2bf(v1.z); o[7] = f2bf(v1.w);
      *(u16x8*)&Bs[pp * 64 + (sl ^ (pp & 7)) * 8] = o;
    }
    __syncthreads();
#pragma unroll
    for (int s = 0; s < 2; ++s) {
      int arow = w * 16 + r16;
      bf16x8 fa = *(const bf16x8*)&As[arow * 64 + (((s * 4 + g) ^ (arow & 7)) * 8)];
#pragma unroll
      for (int n = 0; n < 6; ++n) {
        int brow = n * 16 + r16;
        bf16x8 fb = *(const bf16x8*)&Bs[brow * 64 + (((s * 4 + g) ^ (brow & 7)) * 8)];
        acc[n] = __builtin_amdgcn_mfma_f32_16x16x32_bf16(fa, fb, acc[n], 0, 0, 0);
      }
    }
    __syncthreads();
  }
  const int b0 = w * 16 + g * 4;
#pragma unroll
  for (int n = 0; n < 6; ++n) {
    float bi = blin[f * 96 + n * 16 + r16];
#pragma unroll
    for (int r = 0; r < 4; ++r)
      Y[((size_t)(b0 + r) * 512 + f) * 96 + n * 16 + r16] = acc[n][r] + bi;
  }
}

// ---------- final: denorm + projector ----------
__global__ __launch_bounds__(256) void final_out_k(const float* __restrict__ Y,
                                                   const float* __restrict__ meanb,
                                                   const float* __restrict__ stdb,
                                                   const float* __restrict__ rg,
                                                   const float* __restrict__ rb,
                                                   const float* __restrict__ Wproj,
                                                   const float* __restrict__ bproj,
                                                   float* __restrict__ out) {
  int b = blockIdx.x;
  __shared__ float cs[512];
  __shared__ float kred[4];
  int t = threadIdx.x;
  float kpart = 0.f;
  for (int f = t; f < 512; f += 256) {
    float sd = stdb[b * 512 + f], mn = meanb[b * 512 + f];
    float g = rg[f], rbv = rb[f], wp = Wproj[f];
    float c = wp * sd / g;
    cs[f] = c;
    kpart += wp * mn - c * rbv;
  }
#pragma unroll
  for (int off = 32; off; off >>= 1) kpart += __shfl_down(kpart, off);
  int wid = t >> 6, lane = t & 63;
  if (lane == 0) kred[wid] = kpart;
  __syncthreads();
  float K = kred[0] + kred[1] + kred[2] + kred[3] + bproj[0];
  if (t < 96) {
    float acc = 0.f;
    for (int f = 0; f < 512; ++f) acc = fmaf(cs[f], Y[((size_t)b * 512 + f) * 96 + t], acc);
    out[b * 96 + t] = acc + K;
  }
}

extern "C" void kernel_launch(void* const* d_in, const int* in_sizes, int n_in,
                              void* d_out, int out_size, void* d_ws, size_t ws_size,
                              hipStream_t stream) {
  const float* x    = (const float*)d_in[0];
  const float* rg   = (const float*)d_in[1];
  const float* rb   = (const float*)d_in[2];
  const float* n1g  = (const float*)d_in[3];
  const float* n1b  = (const float*)d_in[4];
  const float* n2g  = (const float*)d_in[5];
  const float* n2b  = (const float*)d_in[6];
  const float* tWq  = (const float*)d_in[7];
  const float* tbq  = (const float*)d_in[8];
  const float* tWk  = (const float*)d_in[9];
  const float* tbk  = (const float*)d_in[10];
  const float* tWv  = (const float*)d_in[11];
  const float* tbv  = (const float*)d_in[12];
  const float* tWo  = (const float*)d_in[13];
  const float* tbo  = (const float*)d_in[14];
  const float* fWq  = (const float*)d_in[15];
  const float* fbq  = (const float*)d_in[16];
  const float* fWk  = (const float*)d_in[17];
  const float* fbk  = (const float*)d_in[18];
  const float* fWv  = (const float*)d_in[19];
  const float* fbv  = (const float*)d_in[20];
  const float* fWo  = (const float*)d_in[21];
  const float* fbo  = (const float*)d_in[22];
  const float* Wlin = (const float*)d_in[23];
  const float* blin = (const float*)d_in[24];
  const float* Wprj = (const float*)d_in[25];
  const float* bprj = (const float*)d_in[26];
  float* out = (float*)d_out;

  const size_t SZ = (size_t)64 * 512 * 512;
  char* p = (char*)d_ws;
  unsigned short* xn  = (unsigned short*)p; p += SZ * 2;   // RevIN'd x, (B,F,L)
  unsigned short* h2  = (unsigned short*)p; p += SZ * 2;   // (B,F,L)
  unsigned short* h3  = (unsigned short*)p; p += SZ * 2;   // (B,F,L)
  unsigned short* abf = (unsigned short*)p; p += SZ * 2;   // LN out / ybuf alias
  unsigned short* q16 = (unsigned short*)p; p += SZ * 2;
  unsigned short* k16 = (unsigned short*)p; p += SZ * 2;
  unsigned short* v16 = (unsigned short*)p; p += SZ * 2;
  unsigned short* wbf = (unsigned short*)p; p += (size_t)8 * 262144 * 2;
  unsigned short* kvt = (unsigned short*)p; p += (size_t)512 * 4096 * 2;
  float* z     = (float*)p;         p += (size_t)512 * 64 * 4;
  float* meanb = (float*)p;         p += 32768 * 4;
  float* stdb  = (float*)p;         p += 32768 * 4;
  float* ybuf  = (float*)abf;       // abf dead before feat_linear

  wconv_k<<<dim3(128, 8), 256, 0, stream>>>(tWq, tWk, tWv, tWo, fWq, fWk, fWv, fWo, wbf);
  revin_xn_k<<<8192, 256, 0, stream>>>(x, rg, rb, meanb, stdb, xn);

  // --- temporal attention block (tokens = l, dim = F) ---
  tln_k<<<dim3(16, 64), 256, 0, stream>>>(xn, n1g, n1b, abf);
  gemm_qkv256_k<<<768, 512, 0, stream>>>(abf, wbf, tbq, tbk, tbv, q16, k16, v16);
  kv_mfma_k<<<512, 256, 0, stream>>>(k16, v16, kvt, z);
  attn_mfma_k<<<256, 512, 0, stream>>>(q16, kvt, z);
  gemm_std256_k<1, 1><<<256, 512, 0, stream>>>(q16, wbf + 3 * 262144, tbo, xn, h2);

  // --- feature attention block (tokens = f, dim = L) ---
  ln_k<<<8192, 256, 0, stream>>>(h2, n2g, n2b, abf);
  gemm_qkv256_k<<<768, 512, 0, stream>>>(abf, wbf + 4 * 262144, fbq, fbk, fbv, q16, k16, v16);
  kv_mfma_k<<<512, 256, 0, stream>>>(k16, v16, kvt, z);
  attn_mfma_k<<<256, 512, 0, stream>>>(q16, kvt, z);
  gemm_std256_k<0, 1><<<256, 512, 0, stream>>>(q16, wbf + 7 * 262144, fbo, h2, h3);

  // tail
  feat_linear_k<<<512, 256, 0, stream>>>(h3, Wlin, blin, ybuf);
  final_out_k<<<64, 256, 0, stream>>>(ybuf, meanb, stdb, rg, rb, Wprj, bprj, out);
}

// Round 13
// 384.377 us; speedup vs baseline: 1.8808x; 1.0367x over previous
//
#include <hip/hip_runtime.h>
#include <hip/hip_bf16.h>
#include <cstdint>
#include <cstddef>

// LinearCrypto MI355X round 13: BK=32 double-buffered GEMM core in SAME 34.8KB
// LDS (counted vmcnt(4), paired-row XOR layout), fused kv+attn kernel.
// B=64, F=512, L=512, P=96, H=8, hd=64, M=B*512=32768

#define EPS_ATTN 1e-6f
#define EPS_LN   1e-5f
#define EPS_REVIN 1e-5f

typedef __attribute__((ext_vector_type(8))) short bf16x8;
typedef __attribute__((ext_vector_type(4))) float f32x4;
typedef __attribute__((ext_vector_type(8))) unsigned short u16x8;

__device__ __forceinline__ float bf2f(unsigned short u) {
  unsigned int x = ((unsigned int)u) << 16;
  return __builtin_bit_cast(float, x);
}
__device__ __forceinline__ unsigned short f2bf(float f) {
  __hip_bfloat16 h = __float2bfloat16(f);
  return __builtin_bit_cast(unsigned short, h);
}
__device__ __forceinline__ void gload16(const void* g, void* l) {
  __builtin_amdgcn_global_load_lds(
      (const __attribute__((address_space(1))) void*)g,
      (__attribute__((address_space(3))) void*)l, 16, 0, 0);
}

// ---------- RevIN stats + normalized bf16 copy xn (B,F,L) ----------
__global__ __launch_bounds__(256) void revin_xn_k(const float* __restrict__ x,
                                                  const float* __restrict__ rg,
                                                  const float* __restrict__ rb,
                                                  float* __restrict__ meanb,
                                                  float* __restrict__ stdb,
                                                  unsigned short* __restrict__ xn) {
  int wid = threadIdx.x >> 6, lane = threadIdx.x & 63;
  int row = blockIdx.x * 4 + wid;               // b*512 + f
  const float* xr = x + (size_t)row * 512 + lane * 8;
  float4 a = *(const float4*)xr;
  float4 c = *(const float4*)(xr + 4);
  float s1 = a.x + a.y + a.z + a.w + c.x + c.y + c.z + c.w;
  float s2 = a.x * a.x + a.y * a.y + a.z * a.z + a.w * a.w +
             c.x * c.x + c.y * c.y + c.z * c.z + c.w * c.w;
#pragma unroll
  for (int off = 1; off < 64; off <<= 1) { s1 += __shfl_xor(s1, off); s2 += __shfl_xor(s2, off); }
  float m = s1 * (1.f / 512.f);
  float var = fmaxf((s2 - 512.f * m * m) * (1.f / 511.f), 0.f);
  float sd = sqrtf(var) + EPS_REVIN;
  int f = row & 511;
  float sc = rg[f] / sd;
  float of = rb[f] - m * sc;
  u16x8 o;
  o[0] = f2bf(a.x * sc + of); o[1] = f2bf(a.y * sc + of);
  o[2] = f2bf(a.z * sc + of); o[3] = f2bf(a.w * sc + of);
  o[4] = f2bf(c.x * sc + of); o[5] = f2bf(c.y * sc + of);
  o[6] = f2bf(c.z * sc + of); o[7] = f2bf(c.w * sc + of);
  *(u16x8*)(xn + (size_t)row * 512 + lane * 8) = o;
  if (lane == 0) { meanb[row] = m; stdb[row] = sd; }
}

// ---------- fused transpose + LayerNorm: xn (B,F,L) -> abf (B,L,F) LN'd ----------
__global__ __launch_bounds__(256) void tln_k(const unsigned short* __restrict__ xn,
                                             const float* __restrict__ g,
                                             const float* __restrict__ bq,
                                             unsigned short* __restrict__ o16) {
  __shared__ unsigned short Ts[32][528] __attribute__((aligned(16)));
  const int b = blockIdx.y, l0 = blockIdx.x * 32;
  const int tid = threadIdx.x;
#pragma unroll
  for (int it = 0; it < 8; ++it) {
    int idx = it * 256 + tid;
    int f = idx >> 2, lc = (idx & 3) * 8;
    u16x8 v = *(const u16x8*)(xn + ((size_t)b * 512 + f) * 512 + l0 + lc);
#pragma unroll
    for (int j = 0; j < 8; ++j) Ts[lc + j][f] = v[j];
  }
  __syncthreads();
  const int l = tid >> 3, q = tid & 7;
  float s1 = 0.f, s2 = 0.f;
#pragma unroll
  for (int i = 0; i < 8; ++i) {
    int c = (i + q) & 7;
    bf16x8 t = *(const bf16x8*)&Ts[l][q * 64 + c * 8];
#pragma unroll
    for (int j = 0; j < 8; ++j) {
      float x = bf2f((unsigned short)t[j]);
      s1 += x; s2 += x * x;
    }
  }
#pragma unroll
  for (int off = 1; off < 8; off <<= 1) { s1 += __shfl_xor(s1, off); s2 += __shfl_xor(s2, off); }
  float m = s1 * (1.f / 512.f);
  float var = fmaxf(s2 * (1.f / 512.f) - m * m, 0.f);
  float iv = 1.f / sqrtf(var + EPS_LN);
#pragma unroll
  for (int i = 0; i < 8; ++i) {
    int c = (i + q) & 7;
    int f8 = q * 64 + c * 8;
    bf16x8 t = *(const bf16x8*)&Ts[l][f8];
    float4 g0 = *(const float4*)(g + f8);
    float4 g1 = *(const float4*)(g + f8 + 4);
    float4 b0 = *(const float4*)(bq + f8);
    float4 b1 = *(const float4*)(bq + f8 + 4);
    u16x8 o;
    o[0] = f2bf((bf2f((unsigned short)t[0]) - m) * iv * g0.x + b0.x);
    o[1] = f2bf((bf2f((unsigned short)t[1]) - m) * iv * g0.y + b0.y);
    o[2] = f2bf((bf2f((unsigned short)t[2]) - m) * iv * g0.z + b0.z);
    o[3] = f2bf((bf2f((unsigned short)t[3]) - m) * iv * g0.w + b0.w);
    o[4] = f2bf((bf2f((unsigned short)t[4]) - m) * iv * g1.x + b1.x);
    o[5] = f2bf((bf2f((unsigned short)t[5]) - m) * iv * g1.y + b1.y);
    o[6] = f2bf((bf2f((unsigned short)t[6]) - m) * iv * g1.z + b1.z);
    o[7] = f2bf((bf2f((unsigned short)t[7]) - m) * iv * g1.w + b1.w);
    *(u16x8*)&Ts[l][f8] = o;
  }
  __syncthreads();
#pragma unroll
  for (int it = 0; it < 8; ++it) {
    int idx = it * 256 + tid;
    int ll = idx >> 6, f8 = (idx & 63) * 8;
    u16x8 v = *(const u16x8*)&Ts[ll][f8];
    *(u16x8*)(o16 + ((size_t)b * 512 + l0 + ll) * 512 + f8) = v;
  }
}

// ---------- fused LayerNorm bf16 -> bf16 ----------
__global__ __launch_bounds__(256) void ln_k(const unsigned short* __restrict__ in,
                                            const float* __restrict__ g,
                                            const float* __restrict__ bq,
                                            unsigned short* __restrict__ o16) {
  int row = blockIdx.x * 4 + (threadIdx.x >> 6);
  int lane = threadIdx.x & 63;
  u16x8 u = *(const u16x8*)(in + (size_t)row * 512 + lane * 8);
  float v[8];
#pragma unroll
  for (int j = 0; j < 8; ++j) v[j] = bf2f(u[j]);
  float s1 = 0.f, s2 = 0.f;
#pragma unroll
  for (int j = 0; j < 8; ++j) { s1 += v[j]; s2 += v[j] * v[j]; }
#pragma unroll
  for (int off = 1; off < 64; off <<= 1) { s1 += __shfl_xor(s1, off); s2 += __shfl_xor(s2, off); }
  float m = s1 * (1.f / 512.f);
  float var = fmaxf(s2 * (1.f / 512.f) - m * m, 0.f);
  float iv = 1.f / sqrtf(var + EPS_LN);
  float4 g0 = *(const float4*)(g + lane * 8);
  float4 g1 = *(const float4*)(g + lane * 8 + 4);
  float4 b0 = *(const float4*)(bq + lane * 8);
  float4 b1 = *(const float4*)(bq + lane * 8 + 4);
  u16x8 o;
  o[0] = f2bf((v[0] - m) * iv * g0.x + b0.x);
  o[1] = f2bf((v[1] - m) * iv * g0.y + b0.y);
  o[2] = f2bf((v[2] - m) * iv * g0.z + b0.z);
  o[3] = f2bf((v[3] - m) * iv * g0.w + b0.w);
  o[4] = f2bf((v[4] - m) * iv * g1.x + b1.x);
  o[5] = f2bf((v[5] - m) * iv * g1.y + b1.y);
  o[6] = f2bf((v[6] - m) * iv * g1.z + b1.z);
  o[7] = f2bf((v[7] - m) * iv * g1.w + b1.w);
  *(u16x8*)(o16 + (size_t)row * 512 + lane * 8) = o;
}

// ---------- convert 8 (512x512) fp32 weights -> bf16 packed ----------
__global__ __launch_bounds__(256) void wconv_k(const float* w0, const float* w1,
                                               const float* w2, const float* w3,
                                               const float* w4, const float* w5,
                                               const float* w6, const float* w7,
                                               unsigned short* __restrict__ out) {
  const float* srcs[8] = {w0, w1, w2, w3, w4, w5, w6, w7};
  const float* s = srcs[blockIdx.y];
  size_t idx = (size_t)blockIdx.x * 2048 + threadIdx.x * 8;
  float4 v0 = *(const float4*)(s + idx);
  float4 v1 = *(const float4*)(s + idx + 4);
  u16x8 o;
  o[0] = f2bf(v0.x); o[1] = f2bf(v0.y); o[2] = f2bf(v0.z); o[3] = f2bf(v0.w);
  o[4] = f2bf(v1.x); o[5] = f2bf(v1.y); o[6] = f2bf(v1.z); o[7] = f2bf(v1.w);
  *(u16x8*)(out + (size_t)blockIdx.y * 262144 + idx) = o;
}

// ========== BK=32 double-buffered GEMM core, 34.8KB LDS, counted vmcnt(4) ====
// LDS tile layout: 64 lines x 64 shorts (line = 2 rows); slot8 = ((row&1)<<2 | g)
// XOR (line&7)  -> ds_read_b128 is 2-way aliased (free). gload dest linear.
__device__ __forceinline__ void stage32(const unsigned short* __restrict__ src,
                                        unsigned short* dst, int tid, int koff) {
#pragma unroll
  for (int c = 0; c < 2; ++c) {
    int idx = c * 256 + tid;
    int line = idx >> 3, s8 = idx & 7;
    int logical = s8 ^ (line & 7);
    int srow = line * 2 + (logical >> 2);
    int gs = logical & 3;
    gload16(src + (size_t)srow * 512 + koff + gs * 8, dst + idx * 8);
  }
}

__device__ __forceinline__ void gemm_core(const unsigned short* __restrict__ A,
                                          const unsigned short* __restrict__ W,
                                          unsigned short* smem,
                                          f32x4 (&acc)[4][4],
                                          int m0, int wrow, int tid) {
  const int w = tid >> 6, lane = tid & 63;
  const int wr = w >> 1, wc = w & 1;
  const int r16 = lane & 15, g = lane >> 4;
  const unsigned short* Ag = A + (size_t)m0 * 512;
  const unsigned short* Wg = W + (size_t)wrow * 512;

  stage32(Ag, smem, tid, 0);
  stage32(Wg, smem + 4096, tid, 0);
  for (int t = 0; t < 16; ++t) {
    unsigned short* bufA = smem + (t & 1) * 8192;
    unsigned short* bufB = bufA + 4096;
    asm volatile("s_barrier" ::: "memory");        // prev readers of next-buf done
    if (t < 15) {
      unsigned short* nA = smem + ((t & 1) ^ 1) * 8192;
      stage32(Ag, nA, tid, (t + 1) * 32);
      stage32(Wg, nA + 4096, tid, (t + 1) * 32);
      asm volatile("s_waitcnt vmcnt(4)" ::: "memory");  // tile t landed; t+1 in flight
    } else {
      asm volatile("s_waitcnt vmcnt(0)" ::: "memory");
    }
    asm volatile("s_barrier" ::: "memory");        // all waves confirmed tile t
    bf16x8 fa[4], fb[4];
#pragma unroll
    for (int i = 0; i < 4; ++i) {
      int row = wr * 64 + i * 16 + r16;
      int line = row >> 1;
      int phys = ((((row & 1) << 2) | g) ^ (line & 7));
      fa[i] = *(const bf16x8*)&bufA[line * 64 + phys * 8];
      int rowb = wc * 64 + i * 16 + r16;
      int lineb = rowb >> 1;
      int physb = ((((rowb & 1) << 2) | g) ^ (lineb & 7));
      fb[i] = *(const bf16x8*)&bufB[lineb * 64 + physb * 8];
    }
#pragma unroll
    for (int i = 0; i < 4; ++i)
#pragma unroll
      for (int j = 0; j < 4; ++j)
        acc[i][j] = __builtin_amdgcn_mfma_f32_16x16x32_bf16(fa[i], fb[j], acc[i][j], 0, 0, 0);
  }
  __syncthreads();   // drain before Cs aliases the buffers
}

// ---------- templated epilogue (Wo GEMMs) ----------
template <int TRANS, int ACT, int RES>
__device__ __forceinline__ void gemm_epilogue(f32x4 (&acc)[4][4],
                                              unsigned short* Cs,   // [128][136]
                                              const float* __restrict__ bias,
                                              const unsigned short* __restrict__ resid,
                                              unsigned short* __restrict__ out,
                                              int m0, int n0, int tid) {
  const int w = tid >> 6, lane = tid & 63;
  const int wr = w >> 1, wc = w & 1;
  const int ro = (lane >> 4) * 4, c16 = lane & 15;
#pragma unroll
  for (int j = 0; j < 4; ++j) {
    int nl = wc * 64 + j * 16 + c16;
    float bi = bias[n0 + nl];
#pragma unroll
    for (int i = 0; i < 4; ++i) {
      int ml = wr * 64 + i * 16 + ro;
#pragma unroll
      for (int r = 0; r < 4; ++r) {
        float v = acc[i][j][r] + bi;
        if constexpr (ACT) v = (v > 0.f) ? v + 1.f : __expf(v);
        if constexpr (TRANS) Cs[nl * 136 + ml + r] = f2bf(v);
        else                 Cs[(ml + r) * 136 + nl] = f2bf(v);
      }
    }
  }
  __syncthreads();
  size_t rowbase; int colbase;
  if constexpr (TRANS) { rowbase = (size_t)((m0 >> 9) * 512 + n0); colbase = m0 & 511; }
  else                 { rowbase = (size_t)m0; colbase = n0; }
#pragma unroll
  for (int c = 0; c < 8; ++c) {
    int idx = c * 256 + tid;
    int rr = idx >> 4, c8 = (idx & 15) * 8;
    u16x8 v = *(const u16x8*)&Cs[rr * 136 + c8];
    size_t gaddr = (rowbase + rr) * 512 + colbase + c8;
    if constexpr (RES) {
      u16x8 rv = *(const u16x8*)(resid + gaddr);
#pragma unroll
      for (int q = 0; q < 8; ++q) v[q] = f2bf(bf2f(v[q]) + bf2f(rv[q]));
    }
    *(u16x8*)(out + gaddr) = v;
  }
}

// ---------- standard GEMM dispatch (Wo): 1D grid 1024, XCD-chunked, n-inner ----------
template <int TRANS, int ACT, int RES>
__global__ __launch_bounds__(256, 4) void gemm_std_k(const unsigned short* __restrict__ A,
                                                     const unsigned short* __restrict__ W,
                                                     const float* __restrict__ bias,
                                                     const unsigned short* __restrict__ resid,
                                                     unsigned short* __restrict__ out) {
  __shared__ unsigned short smem[17408] __attribute__((aligned(16)));
  const int tid = threadIdx.x;
  const int bid = blockIdx.x;
  const int nb = (bid & 7) * 128 + (bid >> 3);   // bijective, 1024 % 8 == 0
  const int m0 = (nb >> 2) * 128;
  const int n0 = (nb & 3) * 128;
  f32x4 acc[4][4] = {};
  gemm_core(A, W, smem, acc, m0, n0, tid);
  gemm_epilogue<TRANS, ACT, RES>(acc, smem, bias, resid, out, m0, n0, tid);
}

// ---------- fused QKV GEMM: grid 3072, 12 n-tiles per A-panel adjacent ----------
__global__ __launch_bounds__(256, 4) void gemm_qkv3_k(const unsigned short* __restrict__ A,
                                                      const unsigned short* __restrict__ Wqkv,
                                                      const float* __restrict__ bq,
                                                      const float* __restrict__ bk,
                                                      const float* __restrict__ bv,
                                                      unsigned short* __restrict__ Q,
                                                      unsigned short* __restrict__ K,
                                                      unsigned short* __restrict__ V) {
  __shared__ unsigned short smem[17408] __attribute__((aligned(16)));
  const int tid = threadIdx.x;
  const unsigned int bid = blockIdx.x;
  const unsigned int nb = (bid & 7) * 384 + (bid >> 3);  // bijective, 3072 % 8 == 0
  const int mi = nb / 12, ni = nb % 12;                  // 12 consecutive share A-panel
  const int m0 = mi * 128;
  const int mat = ni >> 2;                               // 0=Q, 1=K, 2=V
  const int n0 = (ni & 3) * 128;
  f32x4 acc[4][4] = {};
  gemm_core(A, Wqkv, smem, acc, m0, mat * 512 + n0, tid);

  const float* bias = (mat == 0) ? bq : (mat == 1) ? bk : bv;
  unsigned short* out = (mat == 0) ? Q : (mat == 1) ? K : V;
  const bool trans = (mat > 0);
  const bool act = (mat < 2);

  const int w = tid >> 6, lane = tid & 63;
  const int wr = w >> 1, wc = w & 1;
  const int ro = (lane >> 4) * 4, c16 = lane & 15;
  unsigned short* Cs = smem;
#pragma unroll
  for (int j = 0; j < 4; ++j) {
    int nl = wc * 64 + j * 16 + c16;
    float bi = bias[n0 + nl];
#pragma unroll
    for (int i = 0; i < 4; ++i) {
      int ml = wr * 64 + i * 16 + ro;
#pragma unroll
      for (int r = 0; r < 4; ++r) {
        float v = acc[i][j][r] + bi;
        if (act) v = (v > 0.f) ? v + 1.f : __expf(v);
        int row = trans ? nl : (ml + r);
        int col = trans ? (ml + r) : nl;
        Cs[row * 136 + col] = f2bf(v);
      }
    }
  }
  __syncthreads();
  size_t rowbase = trans ? (size_t)((m0 >> 9) * 512 + n0) : (size_t)m0;
  int colbase = trans ? (m0 & 511) : n0;
#pragma unroll
  for (int c = 0; c < 8; ++c) {
    int idx = c * 256 + tid;
    int rr = idx >> 4, c8 = (idx & 15) * 8;
    u16x8 v = *(const u16x8*)&Cs[rr * 136 + c8];
    *(u16x8*)(out + (rowbase + rr) * 512 + colbase + c8) = v;
  }
}

// ---------- fused kv+attn: per (b,h): KVT+Z in LDS, then O in-place over Q ----------
__global__ __launch_bounds__(256) void kv_attn_k(unsigned short* __restrict__ Q16,
                                                 const unsigned short* __restrict__ KT,
                                                 const unsigned short* __restrict__ VT) {
  __shared__ unsigned short kvs[4096] __attribute__((aligned(16)));  // 64 e x 128B
  __shared__ float Zs[64];
  const int bh = blockIdx.x, b = bh >> 3, h = bh & 7;
  const int tid = threadIdx.x, w = tid >> 6, lane = tid & 63;
  const int r16 = lane & 15, g = lane >> 4;

  // phase 1: KVT[e][d] = sum_n VT[e][n]*KT[d][n]; Z[d] = sum_n KT[d][n]
  const unsigned short* vb = VT + ((size_t)bh * 64 + w * 16 + r16) * 512 + g * 8;
  const unsigned short* kb = KT + ((size_t)bh * 64 + r16) * 512 + g * 8;
  const short ob = (short)0x3F80;                 // bf16 1.0
  const bf16x8 onesf = {ob, ob, ob, ob, ob, ob, ob, ob};
  f32x4 acc[4] = {}, zacc[4] = {};
  for (int n0 = 0; n0 < 512; n0 += 32) {
    bf16x8 vf = *(const bf16x8*)(vb + n0);
#pragma unroll
    for (int j = 0; j < 4; ++j) {
      bf16x8 kf = *(const bf16x8*)(kb + (size_t)j * 16 * 512 + n0);
      acc[j] = __builtin_amdgcn_mfma_f32_16x16x32_bf16(vf, kf, acc[j], 0, 0, 0);
      zacc[j] = __builtin_amdgcn_mfma_f32_16x16x32_bf16(onesf, kf, zacc[j], 0, 0, 0);
    }
  }
#pragma unroll
  for (int j = 0; j < 4; ++j)
#pragma unroll
    for (int r = 0; r < 4; ++r) {
      int e = w * 16 + g * 4 + r, d = j * 16 + r16;
      int byte = e * 128 + ((((d >> 3) ^ (e & 7)) << 4)) + (d & 7) * 2;
      *(unsigned short*)((char*)kvs + byte) = f2bf(acc[j][r]);
    }
  if (w == 0 && g == 0) {
#pragma unroll
    for (int j = 0; j < 4; ++j) Zs[j * 16 + r16] = zacc[j][0];
  }
  __syncthreads();

  // phase 2: O = (Q @ KVT^T)/(Q.Z+eps); wave w owns rows w*128..+128 of batch b
#pragma unroll
  for (int i = 0; i < 8; ++i) {
    int mrow = b * 512 + w * 128 + i * 16;
    const unsigned short* qrow = Q16 + (size_t)(mrow + r16) * 512 + h * 64;
    bf16x8 q0 = *(const bf16x8*)(qrow + g * 8);
    bf16x8 q1 = *(const bf16x8*)(qrow + 32 + g * 8);
    float np = 0.f;
#pragma unroll
    for (int q = 0; q < 8; ++q) np = fmaf(bf2f((unsigned short)q0[q]), Zs[g * 8 + q], np);
#pragma unroll
    for (int q = 0; q < 8; ++q) np = fmaf(bf2f((unsigned short)q1[q]), Zs[32 + g * 8 + q], np);
    f32x4 a2[4] = {};
#pragma unroll
    for (int j = 0; j < 4; ++j) {
      int e = j * 16 + r16;
      int byte0 = e * 128, sw = (e & 7) << 4;
      bf16x8 k0 = *(const bf16x8*)((char*)kvs + ((byte0 + g * 16) ^ sw));
      bf16x8 k1 = *(const bf16x8*)((char*)kvs + ((byte0 + 64 + g * 16) ^ sw));
      a2[j] = __builtin_amdgcn_mfma_f32_16x16x32_bf16(q0, k0, a2[j], 0, 0, 0);
      a2[j] = __builtin_amdgcn_mfma_f32_16x16x32_bf16(q1, k1, a2[j], 0, 0, 0);
    }
    np += __shfl_xor(np, 16);
    np += __shfl_xor(np, 32);
    float inv = 1.f / (np + EPS_ATTN);
    float inv4[4];
#pragma unroll
    for (int r = 0; r < 4; ++r) inv4[r] = __shfl(inv, g * 4 + r);
    int orow0 = mrow + g * 4;
#pragma unroll
    for (int j = 0; j < 4; ++j)
#pragma unroll
      for (int r = 0; r < 4; ++r)
        Q16[(size_t)(orow0 + r) * 512 + h * 64 + j * 16 + r16] = f2bf(a2[j][r] * inv4[r]);
  }
}

// ---------- feat_linear via MFMA ----------
__global__ __launch_bounds__(256) void feat_linear_k(const unsigned short* __restrict__ h3,
                                                     const float* __restrict__ Wlin,
                                                     const float* __restrict__ blin,
                                                     float* __restrict__ Y) {
  __shared__ unsigned short As[64 * 64] __attribute__((aligned(16)));
  __shared__ unsigned short Bs[96 * 64] __attribute__((aligned(16)));
  const int f = blockIdx.x;
  const int tid = threadIdx.x;
  const int w = tid >> 6, lane = tid & 63;
  const int r16 = lane & 15, g = lane >> 4;
  const int r8 = lane >> 3, s8 = lane & 7, gs = s8 ^ r8;

  f32x4 acc[6] = {};
  for (int k0 = 0; k0 < 512; k0 += 64) {
#pragma unroll
    for (int c = 0; c < 2; ++c) {
      int row = w * 16 + c * 8 + r8;
      gload16(h3 + ((size_t)row * 512 + f) * 512 + k0 + gs * 8,
              As + (w * 16 + c * 8) * 64);
    }
#pragma unroll
    for (int it = 0; it < 3; ++it) {
      int idx = it * 256 + tid;
      int pp = idx >> 3, sl = idx & 7;
      const float* src = Wlin + ((size_t)f * 96 + pp) * 512 + k0 + sl * 8;
      float4 v0 = *(const float4*)src;
      float4 v1 = *(const float4*)(src + 4);
      u16x8 o;
      o[0] = f2bf(v0.x); o[1] = f2bf(v0.y); o[2] = f2bf(v0.z); o[3] = f2bf(v0.w);
      o[4] = f2bf(v1.x); o[5] = f2bf(v1.y); o[6] = f2bf(v1.z); o[7] = f2bf(v1.w);
      *(u16x8*)&Bs[pp * 64 + (sl ^ (pp & 7)) * 8] = o;
    }
    __syncthreads();
#pragma unroll
    for (int s = 0; s < 2; ++s) {
      int arow = w * 16 + r16;
      bf16x8 fa = *(const bf16x8*)&As[arow * 64 + (((s * 4 + g) ^ (arow & 7)) * 8)];
#pragma unroll
      for (int n = 0; n < 6; ++n) {
        int brow = n * 16 + r16;
        bf16x8 fb = *(const bf16x8*)&Bs[brow * 64 + (((s * 4 + g) ^ (brow & 7)) * 8)];
        acc[n] = __builtin_amdgcn_mfma_f32_16x16x32_bf16(fa, fb, acc[n], 0, 0, 0);
      }
    }
    __syncthreads();
  }
  const int b0 = w * 16 + g * 4;
#pragma unroll
  for (int n = 0; n < 6; ++n) {
    float bi = blin[f * 96 + n * 16 + r16];
#pragma unroll
    for (int r = 0; r < 4; ++r)
      Y[((size_t)(b0 + r) * 512 + f) * 96 + n * 16 + r16] = acc[n][r] + bi;
  }
}

// ---------- final: denorm + projector ----------
__global__ __launch_bounds__(256) void final_out_k(const float* __restrict__ Y,
                                                   const float* __restrict__ meanb,
                                                   const float* __restrict__ stdb,
                                                   const float* __restrict__ rg,
                                                   const float* __restrict__ rb,
                                                   const float* __restrict__ Wproj,
                                                   const float* __restrict__ bproj,
                                                   float* __restrict__ out) {
  int b = blockIdx.x;
  __shared__ float cs[512];
  __shared__ float kred[4];
  int t = threadIdx.x;
  float kpart = 0.f;
  for (int f = t; f < 512; f += 256) {
    float sd = stdb[b * 512 + f], mn = meanb[b * 512 + f];
    float g = rg[f], rbv = rb[f], wp = Wproj[f];
    float c = wp * sd / g;
    cs[f] = c;
    kpart += wp * mn - c * rbv;
  }
#pragma unroll
  for (int off = 32; off; off >>= 1) kpart += __shfl_down(kpart, off);
  int wid = t >> 6, lane = t & 63;
  if (lane == 0) kred[wid] = kpart;
  __syncthreads();
  float K = kred[0] + kred[1] + kred[2] + kred[3] + bproj[0];
  if (t < 96) {
    float acc = 0.f;
    for (int f = 0; f < 512; ++f) acc = fmaf(cs[f], Y[((size_t)b * 512 + f) * 96 + t], acc);
    out[b * 96 + t] = acc + K;
  }
}

extern "C" void kernel_launch(void* const* d_in, const int* in_sizes, int n_in,
                              void* d_out, int out_size, void* d_ws, size_t ws_size,
                              hipStream_t stream) {
  const float* x    = (const float*)d_in[0];
  const float* rg   = (const float*)d_in[1];
  const float* rb   = (const float*)d_in[2];
  const float* n1g  = (const float*)d_in[3];
  const float* n1b  = (const float*)d_in[4];
  const float* n2g  = (const float*)d_in[5];
  const float* n2b  = (const float*)d_in[6];
  const float* tWq  = (const float*)d_in[7];
  const float* tbq  = (const float*)d_in[8];
  const float* tWk  = (const float*)d_in[9];
  const float* tbk  = (const float*)d_in[10];
  const float* tWv  = (const float*)d_in[11];
  const float* tbv  = (const float*)d_in[12];
  const float* tWo  = (const float*)d_in[13];
  const float* tbo  = (const float*)d_in[14];
  const float* fWq  = (const float*)d_in[15];
  const float* fbq  = (const float*)d_in[16];
  const float* fWk  = (const float*)d_in[17];
  const float* fbk  = (const float*)d_in[18];
  const float* fWv  = (const float*)d_in[19];
  const float* fbv  = (const float*)d_in[20];
  const float* fWo  = (const float*)d_in[21];
  const float* fbo  = (const float*)d_in[22];
  const float* Wlin = (const float*)d_in[23];
  const float* blin = (const float*)d_in[24];
  const float* Wprj = (const float*)d_in[25];
  const float* bprj = (const float*)d_in[26];
  float* out = (float*)d_out;

  const size_t SZ = (size_t)64 * 512 * 512;
  char* p = (char*)d_ws;
  unsigned short* xn  = (unsigned short*)p; p += SZ * 2;   // RevIN'd x, (B,F,L)
  unsigned short* h2  = (unsigned short*)p; p += SZ * 2;   // (B,F,L)
  unsigned short* h3  = (unsigned short*)p; p += SZ * 2;   // (B,F,L)
  unsigned short* abf = (unsigned short*)p; p += SZ * 2;   // LN out / ybuf alias
  unsigned short* q16 = (unsigned short*)p; p += SZ * 2;
  unsigned short* k16 = (unsigned short*)p; p += SZ * 2;
  unsigned short* v16 = (unsigned short*)p; p += SZ * 2;
  unsigned short* wbf = (unsigned short*)p; p += (size_t)8 * 262144 * 2;
  float* meanb = (float*)p;         p += 32768 * 4;
  float* stdb  = (float*)p;         p += 32768 * 4;
  float* ybuf  = (float*)abf;       // abf dead before feat_linear

  wconv_k<<<dim3(128, 8), 256, 0, stream>>>(tWq, tWk, tWv, tWo, fWq, fWk, fWv, fWo, wbf);
  revin_xn_k<<<8192, 256, 0, stream>>>(x, rg, rb, meanb, stdb, xn);

  // --- temporal attention block (tokens = l, dim = F) ---
  tln_k<<<dim3(16, 64), 256, 0, stream>>>(xn, n1g, n1b, abf);
  gemm_qkv3_k<<<3072, 256, 0, stream>>>(abf, wbf, tbq, tbk, tbv, q16, k16, v16);
  kv_attn_k<<<512, 256, 0, stream>>>(q16, k16, v16);
  gemm_std_k<1, 0, 1><<<1024, 256, 0, stream>>>(q16, wbf + 3 * 262144, tbo, xn, h2);

  // --- feature attention block (tokens = f, dim = L) ---
  ln_k<<<8192, 256, 0, stream>>>(h2, n2g, n2b, abf);
  gemm_qkv3_k<<<3072, 256, 0, stream>>>(abf, wbf + 4 * 262144, fbq, fbk, fbv, q16, k16, v16);
  kv_attn_k<<<512, 256, 0, stream>>>(q16, k16, v16);
  gemm_std_k<0, 0, 1><<<1024, 256, 0, stream>>>(q16, wbf + 7 * 262144, fbo, h2, h3);

  // tail
  feat_linear_k<<<512, 256, 0, stream>>>(h3, Wlin, blin, ybuf);
  final_out_k<<<64, 256, 0, stream>>>(ybuf, meanb, stdb, rg, rb, Wprj, bprj, out);
}

// Round 14
// 372.377 us; speedup vs baseline: 1.9414x; 1.0322x over previous
//
#include <hip/hip_runtime.h>
#include <hip/hip_bf16.h>
#include <cstdint>
#include <cstddef>

// LinearCrypto MI355X round 14: consolidation — r9's proven BK=64 2-barrier
// GEMM core (79us QKV) + r13's fused kv_attn. Best-known components only.
// B=64, F=512, L=512, P=96, H=8, hd=64, M=B*512=32768

#define EPS_ATTN 1e-6f
#define EPS_LN   1e-5f
#define EPS_REVIN 1e-5f

typedef __attribute__((ext_vector_type(8))) short bf16x8;
typedef __attribute__((ext_vector_type(4))) float f32x4;
typedef __attribute__((ext_vector_type(8))) unsigned short u16x8;

__device__ __forceinline__ float bf2f(unsigned short u) {
  unsigned int x = ((unsigned int)u) << 16;
  return __builtin_bit_cast(float, x);
}
__device__ __forceinline__ unsigned short f2bf(float f) {
  __hip_bfloat16 h = __float2bfloat16(f);
  return __builtin_bit_cast(unsigned short, h);
}
__device__ __forceinline__ void gload16(const void* g, void* l) {
  __builtin_amdgcn_global_load_lds(
      (const __attribute__((address_space(1))) void*)g,
      (__attribute__((address_space(3))) void*)l, 16, 0, 0);
}

// ---------- RevIN stats + normalized bf16 copy xn (B,F,L) ----------
__global__ __launch_bounds__(256) void revin_xn_k(const float* __restrict__ x,
                                                  const float* __restrict__ rg,
                                                  const float* __restrict__ rb,
                                                  float* __restrict__ meanb,
                                                  float* __restrict__ stdb,
                                                  unsigned short* __restrict__ xn) {
  int wid = threadIdx.x >> 6, lane = threadIdx.x & 63;
  int row = blockIdx.x * 4 + wid;               // b*512 + f
  const float* xr = x + (size_t)row * 512 + lane * 8;
  float4 a = *(const float4*)xr;
  float4 c = *(const float4*)(xr + 4);
  float s1 = a.x + a.y + a.z + a.w + c.x + c.y + c.z + c.w;
  float s2 = a.x * a.x + a.y * a.y + a.z * a.z + a.w * a.w +
             c.x * c.x + c.y * c.y + c.z * c.z + c.w * c.w;
#pragma unroll
  for (int off = 1; off < 64; off <<= 1) { s1 += __shfl_xor(s1, off); s2 += __shfl_xor(s2, off); }
  float m = s1 * (1.f / 512.f);
  float var = fmaxf((s2 - 512.f * m * m) * (1.f / 511.f), 0.f);
  float sd = sqrtf(var) + EPS_REVIN;
  int f = row & 511;
  float sc = rg[f] / sd;
  float of = rb[f] - m * sc;
  u16x8 o;
  o[0] = f2bf(a.x * sc + of); o[1] = f2bf(a.y * sc + of);
  o[2] = f2bf(a.z * sc + of); o[3] = f2bf(a.w * sc + of);
  o[4] = f2bf(c.x * sc + of); o[5] = f2bf(c.y * sc + of);
  o[6] = f2bf(c.z * sc + of); o[7] = f2bf(c.w * sc + of);
  *(u16x8*)(xn + (size_t)row * 512 + lane * 8) = o;
  if (lane == 0) { meanb[row] = m; stdb[row] = sd; }
}

// ---------- fused transpose + LayerNorm: xn (B,F,L) -> abf (B,L,F) LN'd ----------
__global__ __launch_bounds__(256) void tln_k(const unsigned short* __restrict__ xn,
                                             const float* __restrict__ g,
                                             const float* __restrict__ bq,
                                             unsigned short* __restrict__ o16) {
  __shared__ unsigned short Ts[32][528] __attribute__((aligned(16)));
  const int b = blockIdx.y, l0 = blockIdx.x * 32;
  const int tid = threadIdx.x;
#pragma unroll
  for (int it = 0; it < 8; ++it) {
    int idx = it * 256 + tid;
    int f = idx >> 2, lc = (idx & 3) * 8;
    u16x8 v = *(const u16x8*)(xn + ((size_t)b * 512 + f) * 512 + l0 + lc);
#pragma unroll
    for (int j = 0; j < 8; ++j) Ts[lc + j][f] = v[j];
  }
  __syncthreads();
  const int l = tid >> 3, q = tid & 7;
  float s1 = 0.f, s2 = 0.f;
#pragma unroll
  for (int i = 0; i < 8; ++i) {
    int c = (i + q) & 7;
    bf16x8 t = *(const bf16x8*)&Ts[l][q * 64 + c * 8];
#pragma unroll
    for (int j = 0; j < 8; ++j) {
      float x = bf2f((unsigned short)t[j]);
      s1 += x; s2 += x * x;
    }
  }
#pragma unroll
  for (int off = 1; off < 8; off <<= 1) { s1 += __shfl_xor(s1, off); s2 += __shfl_xor(s2, off); }
  float m = s1 * (1.f / 512.f);
  float var = fmaxf(s2 * (1.f / 512.f) - m * m, 0.f);
  float iv = 1.f / sqrtf(var + EPS_LN);
#pragma unroll
  for (int i = 0; i < 8; ++i) {
    int c = (i + q) & 7;
    int f8 = q * 64 + c * 8;
    bf16x8 t = *(const bf16x8*)&Ts[l][f8];
    float4 g0 = *(const float4*)(g + f8);
    float4 g1 = *(const float4*)(g + f8 + 4);
    float4 b0 = *(const float4*)(bq + f8);
    float4 b1 = *(const float4*)(bq + f8 + 4);
    u16x8 o;
    o[0] = f2bf((bf2f((unsigned short)t[0]) - m) * iv * g0.x + b0.x);
    o[1] = f2bf((bf2f((unsigned short)t[1]) - m) * iv * g0.y + b0.y);
    o[2] = f2bf((bf2f((unsigned short)t[2]) - m) * iv * g0.z + b0.z);
    o[3] = f2bf((bf2f((unsigned short)t[3]) - m) * iv * g0.w + b0.w);
    o[4] = f2bf((bf2f((unsigned short)t[4]) - m) * iv * g1.x + b1.x);
    o[5] = f2bf((bf2f((unsigned short)t[5]) - m) * iv * g1.y + b1.y);
    o[6] = f2bf((bf2f((unsigned short)t[6]) - m) * iv * g1.z + b1.z);
    o[7] = f2bf((bf2f((unsigned short)t[7]) - m) * iv * g1.w + b1.w);
    *(u16x8*)&Ts[l][f8] = o;
  }
  __syncthreads();
#pragma unroll
  for (int it = 0; it < 8; ++it) {
    int idx = it * 256 + tid;
    int ll = idx >> 6, f8 = (idx & 63) * 8;
    u16x8 v = *(const u16x8*)&Ts[ll][f8];
    *(u16x8*)(o16 + ((size_t)b * 512 + l0 + ll) * 512 + f8) = v;
  }
}

// ---------- fused LayerNorm bf16 -> bf16 ----------
__global__ __launch_bounds__(256) void ln_k(const unsigned short* __restrict__ in,
                                            const float* __restrict__ g,
                                            const float* __restrict__ bq,
                                            unsigned short* __restrict__ o16) {
  int row = blockIdx.x * 4 + (threadIdx.x >> 6);
  int lane = threadIdx.x & 63;
  u16x8 u = *(const u16x8*)(in + (size_t)row * 512 + lane * 8);
  float v[8];
#pragma unroll
  for (int j = 0; j < 8; ++j) v[j] = bf2f(u[j]);
  float s1 = 0.f, s2 = 0.f;
#pragma unroll
  for (int j = 0; j < 8; ++j) { s1 += v[j]; s2 += v[j] * v[j]; }
#pragma unroll
  for (int off = 1; off < 64; off <<= 1) { s1 += __shfl_xor(s1, off); s2 += __shfl_xor(s2, off); }
  float m = s1 * (1.f / 512.f);
  float var = fmaxf(s2 * (1.f / 512.f) - m * m, 0.f);
  float iv = 1.f / sqrtf(var + EPS_LN);
  float4 g0 = *(const float4*)(g + lane * 8);
  float4 g1 = *(const float4*)(g + lane * 8 + 4);
  float4 b0 = *(const float4*)(bq + lane * 8);
  float4 b1 = *(const float4*)(bq + lane * 8 + 4);
  u16x8 o;
  o[0] = f2bf((v[0] - m) * iv * g0.x + b0.x);
  o[1] = f2bf((v[1] - m) * iv * g0.y + b0.y);
  o[2] = f2bf((v[2] - m) * iv * g0.z + b0.z);
  o[3] = f2bf((v[3] - m) * iv * g0.w + b0.w);
  o[4] = f2bf((v[4] - m) * iv * g1.x + b1.x);
  o[5] = f2bf((v[5] - m) * iv * g1.y + b1.y);
  o[6] = f2bf((v[6] - m) * iv * g1.z + b1.z);
  o[7] = f2bf((v[7] - m) * iv * g1.w + b1.w);
  *(u16x8*)(o16 + (size_t)row * 512 + lane * 8) = o;
}

// ---------- convert 8 (512x512) fp32 weights -> bf16 packed ----------
__global__ __launch_bounds__(256) void wconv_k(const float* w0, const float* w1,
                                               const float* w2, const float* w3,
                                               const float* w4, const float* w5,
                                               const float* w6, const float* w7,
                                               unsigned short* __restrict__ out) {
  const float* srcs[8] = {w0, w1, w2, w3, w4, w5, w6, w7};
  const float* s = srcs[blockIdx.y];
  size_t idx = (size_t)blockIdx.x * 2048 + threadIdx.x * 8;
  float4 v0 = *(const float4*)(s + idx);
  float4 v1 = *(const float4*)(s + idx + 4);
  u16x8 o;
  o[0] = f2bf(v0.x); o[1] = f2bf(v0.y); o[2] = f2bf(v0.z); o[3] = f2bf(v0.w);
  o[4] = f2bf(v1.x); o[5] = f2bf(v1.y); o[6] = f2bf(v1.z); o[7] = f2bf(v1.w);
  *(u16x8*)(out + (size_t)blockIdx.y * 262144 + idx) = o;
}

// ---------- GEMM core (r9: single-buffer BK=64, 2 barriers/K-step) ----------
__device__ __forceinline__ void gemm_core(const unsigned short* __restrict__ A,
                                          const unsigned short* __restrict__ W,
                                          unsigned short* smem,
                                          f32x4 (&acc)[4][4],
                                          int m0, int wrow, int tid) {
  const int w = tid >> 6, lane = tid & 63;
  const int wr = w >> 1, wc = w & 1;
  const int r8 = lane >> 3, s8 = lane & 7, gslot = s8 ^ r8;
  const unsigned short* Ag = A + (size_t)(m0 + w * 32 + r8) * 512 + gslot * 8;
  const unsigned short* Wg = W + (size_t)(wrow + w * 32 + r8) * 512 + gslot * 8;
  unsigned short* Asw = smem + w * 2048;
  unsigned short* Bsw = smem + 8192 + w * 2048;
  for (int k0 = 0; k0 < 512; k0 += 64) {
#pragma unroll
    for (int c = 0; c < 4; ++c) {
      gload16(Ag + (size_t)c * 8 * 512 + k0, Asw + c * 512);
      gload16(Wg + (size_t)c * 8 * 512 + k0, Bsw + c * 512);
    }
    __syncthreads();
#pragma unroll
    for (int s = 0; s < 2; ++s) {
      bf16x8 fa[4], fb[4];
#pragma unroll
      for (int i = 0; i < 4; ++i) {
        int ra = wr * 64 + i * 16 + (lane & 15);
        int sa = (s * 4 + (lane >> 4)) ^ (ra & 7);
        fa[i] = *(const bf16x8*)&smem[ra * 64 + sa * 8];
        int rb = wc * 64 + i * 16 + (lane & 15);
        int sb = (s * 4 + (lane >> 4)) ^ (rb & 7);
        fb[i] = *(const bf16x8*)&smem[8192 + rb * 64 + sb * 8];
      }
#pragma unroll
      for (int i = 0; i < 4; ++i)
#pragma unroll
        for (int j = 0; j < 4; ++j)
          acc[i][j] = __builtin_amdgcn_mfma_f32_16x16x32_bf16(fa[i], fb[j], acc[i][j], 0, 0, 0);
    }
    __syncthreads();
  }
}

// ---------- templated epilogue (Wo GEMMs) ----------
template <int TRANS, int ACT, int RES>
__device__ __forceinline__ void gemm_epilogue(f32x4 (&acc)[4][4],
                                              unsigned short* Cs,   // [128][136]
                                              const float* __restrict__ bias,
                                              const unsigned short* __restrict__ resid,
                                              unsigned short* __restrict__ out,
                                              int m0, int n0, int tid) {
  const int w = tid >> 6, lane = tid & 63;
  const int wr = w >> 1, wc = w & 1;
  const int ro = (lane >> 4) * 4, c16 = lane & 15;
#pragma unroll
  for (int j = 0; j < 4; ++j) {
    int nl = wc * 64 + j * 16 + c16;
    float bi = bias[n0 + nl];
#pragma unroll
    for (int i = 0; i < 4; ++i) {
      int ml = wr * 64 + i * 16 + ro;
#pragma unroll
      for (int r = 0; r < 4; ++r) {
        float v = acc[i][j][r] + bi;
        if constexpr (ACT) v = (v > 0.f) ? v + 1.f : __expf(v);
        if constexpr (TRANS) Cs[nl * 136 + ml + r] = f2bf(v);
        else                 Cs[(ml + r) * 136 + nl] = f2bf(v);
      }
    }
  }
  __syncthreads();
  size_t rowbase; int colbase;
  if constexpr (TRANS) { rowbase = (size_t)((m0 >> 9) * 512 + n0); colbase = m0 & 511; }
  else                 { rowbase = (size_t)m0; colbase = n0; }
#pragma unroll
  for (int c = 0; c < 8; ++c) {
    int idx = c * 256 + tid;
    int rr = idx >> 4, c8 = (idx & 15) * 8;
    u16x8 v = *(const u16x8*)&Cs[rr * 136 + c8];
    size_t gaddr = (rowbase + rr) * 512 + colbase + c8;
    if constexpr (RES) {
      u16x8 rv = *(const u16x8*)(resid + gaddr);
#pragma unroll
      for (int q = 0; q < 8; ++q) v[q] = f2bf(bf2f(v[q]) + bf2f(rv[q]));
    }
    *(u16x8*)(out + gaddr) = v;
  }
}

// ---------- standard GEMM dispatch (Wo): 1D grid 1024, XCD-chunked, n-inner ----------
template <int TRANS, int ACT, int RES>
__global__ __launch_bounds__(256, 4) void gemm_std_k(const unsigned short* __restrict__ A,
                                                     const unsigned short* __restrict__ W,
                                                     const float* __restrict__ bias,
                                                     const unsigned short* __restrict__ resid,
                                                     unsigned short* __restrict__ out) {
  __shared__ unsigned short smem[17408] __attribute__((aligned(16)));
  const int tid = threadIdx.x;
  const int bid = blockIdx.x;
  const int nb = (bid & 7) * 128 + (bid >> 3);   // bijective, 1024 % 8 == 0
  const int m0 = (nb >> 2) * 128;
  const int n0 = (nb & 3) * 128;
  f32x4 acc[4][4] = {};
  gemm_core(A, W, smem, acc, m0, n0, tid);
  gemm_epilogue<TRANS, ACT, RES>(acc, smem, bias, resid, out, m0, n0, tid);
}

// ---------- fused QKV GEMM: grid 3072, 12 n-tiles per A-panel adjacent ----------
__global__ __launch_bounds__(256, 4) void gemm_qkv3_k(const unsigned short* __restrict__ A,
                                                      const unsigned short* __restrict__ Wqkv,
                                                      const float* __restrict__ bq,
                                                      const float* __restrict__ bk,
                                                      const float* __restrict__ bv,
                                                      unsigned short* __restrict__ Q,
                                                      unsigned short* __restrict__ K,
                                                      unsigned short* __restrict__ V) {
  __shared__ unsigned short smem[17408] __attribute__((aligned(16)));
  const int tid = threadIdx.x;
  const unsigned int bid = blockIdx.x;
  const unsigned int nb = (bid & 7) * 384 + (bid >> 3);  // bijective, 3072 % 8 == 0
  const int mi = nb / 12, ni = nb % 12;                  // 12 consecutive share A-panel
  const int m0 = mi * 128;
  const int mat = ni >> 2;                               // 0=Q, 1=K, 2=V
  const int n0 = (ni & 3) * 128;
  f32x4 acc[4][4] = {};
  gemm_core(A, Wqkv, smem, acc, m0, mat * 512 + n0, tid);

  const float* bias = (mat == 0) ? bq : (mat == 1) ? bk : bv;
  unsigned short* out = (mat == 0) ? Q : (mat == 1) ? K : V;
  const bool trans = (mat > 0);
  const bool act = (mat < 2);

  const int w = tid >> 6, lane = tid & 63;
  const int wr = w >> 1, wc = w & 1;
  const int ro = (lane >> 4) * 4, c16 = lane & 15;
  unsigned short* Cs = smem;
#pragma unroll
  for (int j = 0; j < 4; ++j) {
    int nl = wc * 64 + j * 16 + c16;
    float bi = bias[n0 + nl];
#pragma unroll
    for (int i = 0; i < 4; ++i) {
      int ml = wr * 64 + i * 16 + ro;
#pragma unroll
      for (int r = 0; r < 4; ++r) {
        float v = acc[i][j][r] + bi;
        if (act) v = (v > 0.f) ? v + 1.f : __expf(v);
        int row = trans ? nl : (ml + r);
        int col = trans ? (ml + r) : nl;
        Cs[row * 136 + col] = f2bf(v);
      }
    }
  }
  __syncthreads();
  size_t rowbase = trans ? (size_t)((m0 >> 9) * 512 + n0) : (size_t)m0;
  int colbase = trans ? (m0 & 511) : n0;
#pragma unroll
  for (int c = 0; c < 8; ++c) {
    int idx = c * 256 + tid;
    int rr = idx >> 4, c8 = (idx & 15) * 8;
    u16x8 v = *(const u16x8*)&Cs[rr * 136 + c8];
    *(u16x8*)(out + (rowbase + rr) * 512 + colbase + c8) = v;
  }
}

// ---------- fused kv+attn: per (b,h): KVT+Z in LDS, then O in-place over Q ----------
__global__ __launch_bounds__(256) void kv_attn_k(unsigned short* __restrict__ Q16,
                                                 const unsigned short* __restrict__ KT,
                                                 const unsigned short* __restrict__ VT) {
  __shared__ unsigned short kvs[4096] __attribute__((aligned(16)));  // 64 e x 128B
  __shared__ float Zs[64];
  const int bh = blockIdx.x, b = bh >> 3, h = bh & 7;
  const int tid = threadIdx.x, w = tid >> 6, lane = tid & 63;
  const int r16 = lane & 15, g = lane >> 4;

  // phase 1: KVT[e][d] = sum_n VT[e][n]*KT[d][n]; Z[d] = sum_n KT[d][n]
  const unsigned short* vb = VT + ((size_t)bh * 64 + w * 16 + r16) * 512 + g * 8;
  const unsigned short* kb = KT + ((size_t)bh * 64 + r16) * 512 + g * 8;
  const short ob = (short)0x3F80;                 // bf16 1.0
  const bf16x8 onesf = {ob, ob, ob, ob, ob, ob, ob, ob};
  f32x4 acc[4] = {}, zacc[4] = {};
  for (int n0 = 0; n0 < 512; n0 += 32) {
    bf16x8 vf = *(const bf16x8*)(vb + n0);
#pragma unroll
    for (int j = 0; j < 4; ++j) {
      bf16x8 kf = *(const bf16x8*)(kb + (size_t)j * 16 * 512 + n0);
      acc[j] = __builtin_amdgcn_mfma_f32_16x16x32_bf16(vf, kf, acc[j], 0, 0, 0);
      zacc[j] = __builtin_amdgcn_mfma_f32_16x16x32_bf16(onesf, kf, zacc[j], 0, 0, 0);
    }
  }
#pragma unroll
  for (int j = 0; j < 4; ++j)
#pragma unroll
    for (int r = 0; r < 4; ++r) {
      int e = w * 16 + g * 4 + r, d = j * 16 + r16;
      int byte = e * 128 + ((((d >> 3) ^ (e & 7)) << 4)) + (d & 7) * 2;
      *(unsigned short*)((char*)kvs + byte) = f2bf(acc[j][r]);
    }
  if (w == 0 && g == 0) {
#pragma unroll
    for (int j = 0; j < 4; ++j) Zs[j * 16 + r16] = zacc[j][0];
  }
  __syncthreads();

  // phase 2: O = (Q @ KVT^T)/(Q.Z+eps); wave w owns rows w*128..+128 of batch b
#pragma unroll
  for (int i = 0; i < 8; ++i) {
    int mrow = b * 512 + w * 128 + i * 16;
    const unsigned short* qrow = Q16 + (size_t)(mrow + r16) * 512 + h * 64;
    bf16x8 q0 = *(const bf16x8*)(qrow + g * 8);
    bf16x8 q1 = *(const bf16x8*)(qrow + 32 + g * 8);
    float np = 0.f;
#pragma unroll
    for (int q = 0; q < 8; ++q) np = fmaf(bf2f((unsigned short)q0[q]), Zs[g * 8 + q], np);
#pragma unroll
    for (int q = 0; q < 8; ++q) np = fmaf(bf2f((unsigned short)q1[q]), Zs[32 + g * 8 + q], np);
    f32x4 a2[4] = {};
#pragma unroll
    for (int j = 0; j < 4; ++j) {
      int e = j * 16 + r16;
      int byte0 = e * 128, sw = (e & 7) << 4;
      bf16x8 k0 = *(const bf16x8*)((char*)kvs + ((byte0 + g * 16) ^ sw));
      bf16x8 k1 = *(const bf16x8*)((char*)kvs + ((byte0 + 64 + g * 16) ^ sw));
      a2[j] = __builtin_amdgcn_mfma_f32_16x16x32_bf16(q0, k0, a2[j], 0, 0, 0);
      a2[j] = __builtin_amdgcn_mfma_f32_16x16x32_bf16(q1, k1, a2[j], 0, 0, 0);
    }
    np += __shfl_xor(np, 16);
    np += __shfl_xor(np, 32);
    float inv = 1.f / (np + EPS_ATTN);
    float inv4[4];
#pragma unroll
    for (int r = 0; r < 4; ++r) inv4[r] = __shfl(inv, g * 4 + r);
    int orow0 = mrow + g * 4;
#pragma unroll
    for (int j = 0; j < 4; ++j)
#pragma unroll
      for (int r = 0; r < 4; ++r)
        Q16[(size_t)(orow0 + r) * 512 + h * 64 + j * 16 + r16] = f2bf(a2[j][r] * inv4[r]);
  }
}

// ---------- feat_linear via MFMA ----------
__global__ __launch_bounds__(256) void feat_linear_k(const unsigned short* __restrict__ h3,
                                                     const float* __restrict__ Wlin,
                                                     const float* __restrict__ blin,
                                                     float* __restrict__ Y) {
  __shared__ unsigned short As[64 * 64] __attribute__((aligned(16)));
  __shared__ unsigned short Bs[96 * 64] __attribute__((aligned(16)));
  const int f = blockIdx.x;
  const int tid = threadIdx.x;
  const int w = tid >> 6, lane = tid & 63;
  const int r16 = lane & 15, g = lane >> 4;
  const int r8 = lane >> 3, s8 = lane & 7, gs = s8 ^ r8;

  f32x4 acc[6] = {};
  for (int k0 = 0; k0 < 512; k0 += 64) {
#pragma unroll
    for (int c = 0; c < 2; ++c) {
      int row = w * 16 + c * 8 + r8;
      gload16(h3 + ((size_t)row * 512 + f) * 512 + k0 + gs * 8,
              As + (w * 16 + c * 8) * 64);
    }
#pragma unroll
    for (int it = 0; it < 3; ++it) {
      int idx = it * 256 + tid;
      int pp = idx >> 3, sl = idx & 7;
      const float* src = Wlin + ((size_t)f * 96 + pp) * 512 + k0 + sl * 8;
      float4 v0 = *(const float4*)src;
      float4 v1 = *(const float4*)(src + 4);
      u16x8 o;
      o[0] = f2bf(v0.x); o[1] = f2bf(v0.y); o[2] = f2bf(v0.z); o[3] = f2bf(v0.w);
      o[4] = f2bf(v1.x); o[5] = f2bf(v1.y); o[6] = f2bf(v1.z); o[7] = f2bf(v1.w);
      *(u16x8*)&Bs[pp * 64 + (sl ^ (pp & 7)) * 8] = o;
    }
    __syncthreads();
#pragma unroll
    for (int s = 0; s < 2; ++s) {
      int arow = w * 16 + r16;
      bf16x8 fa = *(const bf16x8*)&As[arow * 64 + (((s * 4 + g) ^ (arow & 7)) * 8)];
#pragma unroll
      for (int n = 0; n < 6; ++n) {
        int brow = n * 16 + r16;
        bf16x8 fb = *(const bf16x8*)&Bs[brow * 64 + (((s * 4 + g) ^ (brow & 7)) * 8)];
        acc[n] = __builtin_amdgcn_mfma_f32_16x16x32_bf16(fa, fb, acc[n], 0, 0, 0);
      }
    }
    __syncthreads();
  }
  const int b0 = w * 16 + g * 4;
#pragma unroll
  for (int n = 0; n < 6; ++n) {
    float bi = blin[f * 96 + n * 16 + r16];
#pragma unroll
    for (int r = 0; r < 4; ++r)
      Y[((size_t)(b0 + r) * 512 + f) * 96 + n * 16 + r16] = acc[n][r] + bi;
  }
}

// ---------- final: denorm + projector ----------
__global__ __launch_bounds__(256) void final_out_k(const float* __restrict__ Y,
                                                   const float* __restrict__ meanb,
                                                   const float* __restrict__ stdb,
                                                   const float* __restrict__ rg,
                                                   const float* __restrict__ rb,
                                                   const float* __restrict__ Wproj,
                                                   const float* __restrict__ bproj,
                                                   float* __restrict__ out) {
  int b = blockIdx.x;
  __shared__ float cs[512];
  __shared__ float kred[4];
  int t = threadIdx.x;
  float kpart = 0.f;
  for (int f = t; f < 512; f += 256) {
    float sd = stdb[b * 512 + f], mn = meanb[b * 512 + f];
    float g = rg[f], rbv = rb[f], wp = Wproj[f];
    float c = wp * sd / g;
    cs[f] = c;
    kpart += wp * mn - c * rbv;
  }
#pragma unroll
  for (int off = 32; off; off >>= 1) kpart += __shfl_down(kpart, off);
  int wid = t >> 6, lane = t & 63;
  if (lane == 0) kred[wid] = kpart;
  __syncthreads();
  float K = kred[0] + kred[1] + kred[2] + kred[3] + bproj[0];
  if (t < 96) {
    float acc = 0.f;
    for (int f = 0; f < 512; ++f) acc = fmaf(cs[f], Y[((size_t)b * 512 + f) * 96 + t], acc);
    out[b * 96 + t] = acc + K;
  }
}

extern "C" void kernel_launch(void* const* d_in, const int* in_sizes, int n_in,
                              void* d_out, int out_size, void* d_ws, size_t ws_size,
                              hipStream_t stream) {
  const float* x    = (const float*)d_in[0];
  const float* rg   = (const float*)d_in[1];
  const float* rb   = (const float*)d_in[2];
  const float* n1g  = (const float*)d_in[3];
  const float* n1b  = (const float*)d_in[4];
  const float* n2g  = (const float*)d_in[5];
  const float* n2b  = (const float*)d_in[6];
  const float* tWq  = (const float*)d_in[7];
  const float* tbq  = (const float*)d_in[8];
  const float* tWk  = (const float*)d_in[9];
  const float* tbk  = (const float*)d_in[10];
  const float* tWv  = (const float*)d_in[11];
  const float* tbv  = (const float*)d_in[12];
  const float* tWo  = (const float*)d_in[13];
  const float* tbo  = (const float*)d_in[14];
  const float* fWq  = (const float*)d_in[15];
  const float* fbq  = (const float*)d_in[16];
  const float* fWk  = (const float*)d_in[17];
  const float* fbk  = (const float*)d_in[18];
  const float* fWv  = (const float*)d_in[19];
  const float* fbv  = (const float*)d_in[20];
  const float* fWo  = (const float*)d_in[21];
  const float* fbo  = (const float*)d_in[22];
  const float* Wlin = (const float*)d_in[23];
  const float* blin = (const float*)d_in[24];
  const float* Wprj = (const float*)d_in[25];
  const float* bprj = (const float*)d_in[26];
  float* out = (float*)d_out;

  const size_t SZ = (size_t)64 * 512 * 512;
  char* p = (char*)d_ws;
  unsigned short* xn  = (unsigned short*)p; p += SZ * 2;   // RevIN'd x, (B,F,L)
  unsigned short* h2  = (unsigned short*)p; p += SZ * 2;   // (B,F,L)
  unsigned short* h3  = (unsigned short*)p; p += SZ * 2;   // (B,F,L)
  unsigned short* abf = (unsigned short*)p; p += SZ * 2;   // LN out / ybuf alias
  unsigned short* q16 = (unsigned short*)p; p += SZ * 2;
  unsigned short* k16 = (unsigned short*)p; p += SZ * 2;
  unsigned short* v16 = (unsigned short*)p; p += SZ * 2;
  unsigned short* wbf = (unsigned short*)p; p += (size_t)8 * 262144 * 2;
  float* meanb = (float*)p;         p += 32768 * 4;
  float* stdb  = (float*)p;         p += 32768 * 4;
  float* ybuf  = (float*)abf;       // abf dead before feat_linear

  wconv_k<<<dim3(128, 8), 256, 0, stream>>>(tWq, tWk, tWv, tWo, fWq, fWk, fWv, fWo, wbf);
  revin_xn_k<<<8192, 256, 0, stream>>>(x, rg, rb, meanb, stdb, xn);

  // --- temporal attention block (tokens = l, dim = F) ---
  tln_k<<<dim3(16, 64), 256, 0, stream>>>(xn, n1g, n1b, abf);
  gemm_qkv3_k<<<3072, 256, 0, stream>>>(abf, wbf, tbq, tbk, tbv, q16, k16, v16);
  kv_attn_k<<<512, 256, 0, stream>>>(q16, k16, v16);
  gemm_std_k<1, 0, 1><<<1024, 256, 0, stream>>>(q16, wbf + 3 * 262144, tbo, xn, h2);

  // --- feature attention block (tokens = f, dim = L) ---
  ln_k<<<8192, 256, 0, stream>>>(h2, n2g, n2b, abf);
  gemm_qkv3_k<<<3072, 256, 0, stream>>>(abf, wbf + 4 * 262144, fbq, fbk, fbv, q16, k16, v16);
  kv_attn_k<<<512, 256, 0, stream>>>(q16, k16, v16);
  gemm_std_k<0, 0, 1><<<1024, 256, 0, stream>>>(q16, wbf + 7 * 262144, fbo, h2, h3);

  // tail
  feat_linear_k<<<512, 256, 0, stream>>>(h3, Wlin, blin, ybuf);
  final_out_k<<<64, 256, 0, stream>>>(ybuf, meanb, stdb, rg, rb, Wprj, bprj, out);
}